// Round 9
// baseline (2720.090 us; speedup 1.0000x reference)
//
#include <hip/hip_runtime.h>

#define BB 8
#define NN 8192
#define RR 2048
#define KK 4
#define LL 4
#define TC 61
#define EPSF 1e-6f
#define BN (BB*NN)
#define OUTN (BN*3)
#define TW 16
#define PP 20

typedef unsigned short u16;
typedef unsigned int u32;
typedef _Float16 h2f __attribute__((ext_vector_type(2)));

__device__ __forceinline__ float fd2(u32 a, u32 b, float acc) {
#if __has_builtin(__builtin_amdgcn_fdot2)
  return __builtin_amdgcn_fdot2(__builtin_bit_cast(h2f, a), __builtin_bit_cast(h2f, b), acc, false);
#else
  h2f A = __builtin_bit_cast(h2f, a), B = __builtin_bit_cast(h2f, b);
  return acc + (float)A.x * (float)B.x + (float)A.y * (float)B.y;
#endif
}
__device__ __forceinline__ float dot32(const u32* g, const u32* w) {
  float a0=0.f, a1=0.f, a2=0.f, a3=0.f;
#pragma unroll
  for (int c = 0; c < 32; c += 4) {
    a0 = fd2(g[c+0], w[c+0], a0);
    a1 = fd2(g[c+1], w[c+1], a1);
    a2 = fd2(g[c+2], w[c+2], a2);
    a3 = fd2(g[c+3], w[c+3], a3);
  }
  return (a0+a1)+(a2+a3);
}
__device__ __forceinline__ u32 packf16(float a, float b) {
  h2f h; h.x = (_Float16)a; h.y = (_Float16)b; return __builtin_bit_cast(u32, h);
}
__device__ __forceinline__ u16 f16b(float a) {
  _Float16 h = (_Float16)a; return __builtin_bit_cast(u16, h);
}
__device__ __forceinline__ float2 unpk(u32 a) {
  h2f h = __builtin_bit_cast(h2f, a); return make_float2((float)h.x, (float)h.y);
}
__device__ __forceinline__ int kmax_of(int n) {
  int aatom = n & 3, rres = n >> 2;
  return (aatom==0) ? (rres==0 ? 2 : 3)
       : (aatom==1) ? 3
       : (aatom==2) ? (rres==RR-1 ? 3 : 4) : 2;
}

__global__ __launch_bounds__(256) void k_const(float* out, float v) {
  int i = blockIdx.x*256 + threadIdx.x;
  if (i < OUTN) out[i] = v;
}

// ---------- weight f16 pre-pack ----------
struct WSrc { const float* m[11]; };
__global__ __launch_bounds__(256) void k_prep(WSrc s, u32* W16) {
  int i = blockIdx.x*256 + threadIdx.x;   // 139264 items
  if (i < 73728) {                        // 9 matrices [64 x 64] per layer, pack over dim0
    int m = i >> 13, rr = i & 8191, l = rr >> 11, r2 = rr & 2047;
    int c2 = r2 >> 6, col = r2 & 63;
    const float* src = s.m[m] + l*4096;
    W16[i] = packf16(src[(2*c2)*64 + col], src[(2*c2+1)*64 + col]);
  } else if (i < 106496) {                // ffa [64 x 256], pack over c
    int j2 = i - 73728; int l = j2 >> 13, r2 = j2 & 8191;
    int c2 = r2 >> 8, j = r2 & 255;
    const float* src = s.m[9] + l*16384;
    W16[i] = packf16(src[(2*c2)*256 + j], src[(2*c2+1)*256 + j]);
  } else {                                // ffb [256 x 64], pack over j
    int j2 = i - 106496; int l = j2 >> 13, r2 = j2 & 8191;
    int jp = r2 >> 6, e = r2 & 63;
    const float* src = s.m[10] + l*16384;
    W16[i] = packf16(src[(2*jp)*64 + e], src[(2*jp+1)*64 + e]);
  }
}

// ---------- time embedding MLP ----------
__global__ __launch_bounds__(128) void k_te(const float* t, const float* w1, const float* b1,
                                            const float* w2, const float* b2, float* te2) {
  __shared__ float s0[128], s1[128];
  int j = threadIdx.x;
  for (int b = 0; b < BB; ++b) {
    float tv = t[b];
    int i = j & 63;
    float fr = expf(-9.210340371976184f * (float)i * (1.0f/64.0f));
    float em = tv * fr;
    s0[j] = (j < 64) ? sinf(em) : cosf(em);
    __syncthreads();
    float acc = b1[j];
    for (int i2 = 0; i2 < 128; ++i2) acc += s0[i2] * w1[i2*128 + j];
    s1[j] = acc / (1.f + expf(-acc));
    __syncthreads();
    if (j < TC) {
      float a2 = b2[j];
      for (int i2 = 0; i2 < 128; ++i2) a2 += s1[i2] * w2[i2*TC + j];
      te2[b*TC + j] = a2;
    }
    __syncthreads();
  }
}

// ---------- init f0p/f1p (packed f16 pairs) + rhat ----------
__global__ __launch_bounds__(256) void k_init(const float* x, const float* win1, const int* nbr,
                                              const float* te2, u32* f0p, u32* f1p, float* rhat) {
  int tok = blockIdx.x*8 + (threadIdx.x >> 5);
  int c2 = threadIdx.x & 31;
  int b = tok >> 13, n = tok & (NN-1);
  float x0 = x[tok*3+0], x1 = x[tok*3+1], x2 = x[tok*3+2];
  int ca = 2*c2, cb = 2*c2+1;
  float va = (ca < TC) ? te2[b*TC + ca] : (ca == 61 ? x0 : (ca == 62 ? x1 : x2));
  float vb = (cb < TC) ? te2[b*TC + cb] : (cb == 61 ? x0 : (cb == 62 ? x1 : x2));
  f0p[tok*32 + c2] = packf16(va, vb);
  float wa = win1[ca], wb = win1[cb];
  f1p[(tok*3+0)*32 + c2] = packf16(x0*wa, x0*wb);
  f1p[(tok*3+1)*32 + c2] = packf16(x1*wa, x1*wb);
  f1p[(tok*3+2)*32 + c2] = packf16(x2*wa, x2*wb);
  if (c2 < KK) {
    int tj = b*NN + nbr[n*KK + c2];
    float rx = x[tj*3+0] - x0, ry = x[tj*3+1] - x1, rz = x[tj*3+2] - x2;
    float ir = rsqrtf(rx*rx + ry*ry + rz*rz + EPSF);
    rhat[(tok*KK+c2)*3 + 0] = rx * ir;
    rhat[(tok*KK+c2)*3 + 1] = ry * ir;
    rhat[(tok*KK+c2)*3 + 2] = rz * ir;
  }
}

// ---------- fused layer ----------
__global__ __launch_bounds__(256, 4) void k_layer(const u32* W16, int l,
    const int* nbr, const float* rhat, u32* f0p, u32* f1p) {
  __shared__ __align__(16) char SB[40960];
  u32* sg0 = (u32*)(SB);             // 20*32 u32 = 2560
  u32* sg1 = (u32*)(SB + 2560);      // 3*20*32 = 7680
  u16* sk0 = (u16*)(SB + 10240);     // 20*64 u16 = 2560
  u16* sv0 = (u16*)(SB + 12800);     // 2560
  u16* sk1 = (u16*)(SB + 15360);     // 3*20*64 = 7680
  u16* sv1 = (u16*)(SB + 23040);     // 7680
  u16* sq0 = (u16*)(SB + 30720);     // 16*64 = 2048
  u16* sq1 = (u16*)(SB + 32768);     // 3*16*64 = 6144
  float* srh = (float*)(SB + 38912); // 16*12 f32 = 768
  float* sa  = (float*)(SB + 39680); // 16*16 f32 = 1024
  int*  spk  = (int*)(SB + 40704);   // 16*4 = 256  -> total 40960
  // phase aliases (lifetimes disjoint, sync-separated)
  u32* so0   = (u32*)(SB);           // 16*32 (over sg0)
  u32* so1   = (u32*)(SB + 2560);    // 3*16*32 (over sg1)
  float* sf0n = (float*)(SB + 10240);// 16*64 f32 (over sk0/sv0)
  float* sf1n = (float*)(SB + 15360);// 3*16*64 f32 (over sk1/sv1)
  u32* sgf   = (u32*)(SB);           // (over so0)
  u32* sg1f  = (u32*)(SB + 2560);    // (over so1)
  u16* sh    = (u16*)(SB + 30720);   // 16*256 u16 (over sq0+sq1)

  const int tid = threadIdx.x;
  // XCD-contiguous tile mapping: blocks %8 round-robin over XCDs -> give each
  // XCD a contiguous 512-tile (8192-token) span so halo lines stay in one L2.
  const int tile = ((blockIdx.x & 7) << 9) | (blockIdx.x >> 3);
  const int gb = tile * TW;
  const int nsin = gb & (NN-1);
  const int bbase = gb - nsin;

  const u32 *pq0 = W16 + 0*8192 + l*2048, *pk0w = W16 + 1*8192 + l*2048, *pv0w = W16 + 2*8192 + l*2048;
  const u32 *pq1 = W16 + 3*8192 + l*2048, *pk1w = W16 + 4*8192 + l*2048, *pv1w = W16 + 5*8192 + l*2048;
  const u32 *po0 = W16 + 6*8192 + l*2048, *po1 = W16 + 7*8192 + l*2048, *pf1w = W16 + 8*8192 + l*2048;
  const u32 *pa = W16 + 73728 + l*8192, *pb = W16 + 106496 + l*8192;

  // ---- phase 1: LN/vnorm for PP tokens (8-lane groups), pack f16; stage rhat, nbr ----
  {
    int g = tid >> 3, ln = tid & 7;
    if (g < PP) {
      int p = g;
      int nl = nsin + p - 2; nl = nl < 0 ? 0 : (nl > NN-1 ? NN-1 : nl);
      int tok = bbase + nl;
      uint4 A0 = *((const uint4*)(f0p + tok*32 + ln*4));
      float v0[8];
      { float2 t0=unpk(A0.x), t1=unpk(A0.y), t2=unpk(A0.z), t3=unpk(A0.w);
        v0[0]=t0.x; v0[1]=t0.y; v0[2]=t1.x; v0[3]=t1.y; v0[4]=t2.x; v0[5]=t2.y; v0[6]=t3.x; v0[7]=t3.y; }
      float s = 0.f, s2 = 0.f, ss = 0.f;
#pragma unroll
      for (int i = 0; i < 8; ++i) { s += v0[i]; s2 += v0[i]*v0[i]; }
      float v1[24];
#pragma unroll
      for (int v = 0; v < 3; ++v) {
        uint4 A1 = *((const uint4*)(f1p + (tok*3+v)*32 + ln*4));
        float2 t0=unpk(A1.x), t1=unpk(A1.y), t2=unpk(A1.z), t3=unpk(A1.w);
        v1[v*8+0]=t0.x; v1[v*8+1]=t0.y; v1[v*8+2]=t1.x; v1[v*8+3]=t1.y;
        v1[v*8+4]=t2.x; v1[v*8+5]=t2.y; v1[v*8+6]=t3.x; v1[v*8+7]=t3.y;
#pragma unroll
        for (int i = 0; i < 8; ++i) ss += v1[v*8+i]*v1[v*8+i];
      }
#pragma unroll
      for (int m = 1; m < 8; m <<= 1) {
        s  += __shfl_xor(s,  m, 64);
        s2 += __shfl_xor(s2, m, 64);
        ss += __shfl_xor(ss, m, 64);
      }
      float mu = s * (1.f/64.f);
      float ri = rsqrtf(fmaxf(s2*(1.f/64.f) - mu*mu, 0.f) + EPSF);
      float vs = rsqrtf(ss*(1.f/64.f) + EPSF);
#pragma unroll
      for (int i = 0; i < 4; ++i)
        sg0[p*32 + ln*4 + i] = packf16((v0[2*i]-mu)*ri, (v0[2*i+1]-mu)*ri);
#pragma unroll
      for (int v = 0; v < 3; ++v)
#pragma unroll
        for (int i = 0; i < 4; ++i)
          sg1[(v*PP+p)*32 + ln*4 + i] = packf16(v1[v*8+2*i]*vs, v1[v*8+2*i+1]*vs);
    }
    if (tid < 192) { int tk = tid/12; srh[tid] = rhat[(gb+tk)*12 + (tid - tk*12)]; }
    if (tid < 64) {
      int tk = tid >> 2, k = tid & 3;
      int pv = nbr[(nsin+tk)*4 + k] - nsin + 2;
      spk[tid] = pv < 0 ? 0 : (pv > PP-1 ? PP-1 : pv);
    }
  }
  __syncthreads();

  // ---- phase 2: QKV projections (weight column in regs) ----
  {
    int e = tid & 63, grp = tid >> 6;
    u32 w[32];
#pragma unroll 8
    for (int c = 0; c < 32; ++c) w[c] = pq0[c*64+e];
    for (int tk = grp; tk < TW; tk += 4)
      sq0[tk*64+e] = f16b(dot32(sg0 + (tk+2)*32, w));
#pragma unroll 8
    for (int c = 0; c < 32; ++c) w[c] = pk0w[c*64+e];
    for (int p = grp; p < PP; p += 4)
      sk0[p*64+e] = f16b(dot32(sg0 + p*32, w));
#pragma unroll 8
    for (int c = 0; c < 32; ++c) w[c] = pv0w[c*64+e];
    for (int p = grp; p < PP; p += 4)
      sv0[p*64+e] = f16b(dot32(sg0 + p*32, w));
#pragma unroll 8
    for (int c = 0; c < 32; ++c) w[c] = pq1[c*64+e];
    for (int i = grp; i < 3*TW; i += 4) {
      int v = i >> 4, tk = i & 15;
      sq1[(v*TW+tk)*64+e] = f16b(dot32(sg1 + (v*PP + tk+2)*32, w));
    }
#pragma unroll 8
    for (int c = 0; c < 32; ++c) w[c] = pk1w[c*64+e];
    for (int v = 0; v < 3; ++v)
      for (int p = grp; p < PP; p += 4)
        sk1[(v*PP+p)*64+e] = f16b(dot32(sg1 + (v*PP + p)*32, w));
#pragma unroll 8
    for (int c = 0; c < 32; ++c) w[c] = pv1w[c*64+e];
    for (int v = 0; v < 3; ++v)
      for (int p = grp; p < PP; p += 4)
        sv1[(v*PP+p)*64+e] = f16b(dot32(sg1 + (v*PP + p)*32, w));
  }
  __syncthreads();

  // ---- phase 3: QK^T logits ----
  {
    int it = tid;
    int tk = it >> 4, h = (it >> 2) & 3, k = it & 3;
    int pk = spk[tk*4+k];
    const u32* qp = (const u32*)sq0 + tk*32 + h*8;
    const u32* kp = (const u32*)sk0 + pk*32 + h*8;
    float acc0 = 0.f, acc1 = 0.f;
#pragma unroll
    for (int d = 0; d < 8; d += 2) {
      acc0 = fd2(qp[d],   kp[d],   acc0);
      acc1 = fd2(qp[d+1], kp[d+1], acc1);
    }
#pragma unroll
    for (int v = 0; v < 3; ++v) {
      const u32* q1p = (const u32*)sq1 + (v*TW+tk)*32 + h*8;
      const u32* k1p = (const u32*)sk1 + (v*PP+pk)*32 + h*8;
#pragma unroll
      for (int d = 0; d < 8; d += 2) {
        acc0 = fd2(q1p[d],   k1p[d],   acc0);
        acc1 = fd2(q1p[d+1], k1p[d+1], acc1);
      }
    }
    sa[it] = (acc0 + acc1) * 0.25f;
  }
  __syncthreads();

  // ---- phase 4: softmax ----
  if (tid < 64) {
    int tk = tid >> 2, h = tid & 3;
    int km = kmax_of(nsin + tk);
    float* row = sa + tk*16 + h*4;
    float mx = -1e30f;
    for (int k = 0; k < km; ++k) mx = fmaxf(mx, row[k]);
    float s = 0.f, aw[4];
#pragma unroll
    for (int k = 0; k < 4; ++k) { aw[k] = (k < km) ? expf(row[k]-mx) : 0.f; s += aw[k]; }
    float inv = 1.f / s;
#pragma unroll
    for (int k = 0; k < 4; ++k) row[k] = aw[k]*inv;
  }
  __syncthreads();

  // ---- phase 5: AV ----
  for (int it = tid; it < TW*32; it += 256) {
    int tk = it >> 5, ep = it & 31, h = ep >> 3;
    const float* arow = sa + tk*16 + h*4;
    float o0a=0,o0b=0,o1a[3]={0,0,0},o1b[3]={0,0,0};
#pragma unroll
    for (int k = 0; k < 4; ++k) {
      float a = arow[k];
      int pk = spk[tk*4+k];
      float2 v0 = unpk(((const u32*)sv0)[pk*32+ep]);
      float vx[3], vy[3];
#pragma unroll
      for (int v = 0; v < 3; ++v) {
        float2 t = unpk(((const u32*)sv1)[(v*PP+pk)*32+ep]);
        vx[v]=t.x; vy[v]=t.y;
      }
      const float* rh = srh + tk*12 + k*3;
      float vda = vx[0]*rh[0]+vx[1]*rh[1]+vx[2]*rh[2];
      float vdb = vy[0]*rh[0]+vy[1]*rh[1]+vy[2]*rh[2];
      o0a += a*(v0.x + vda); o0b += a*(v0.y + vdb);
#pragma unroll
      for (int v = 0; v < 3; ++v) {
        o1a[v] += a*(vx[v] + v0.x*rh[v]);
        o1b[v] += a*(vy[v] + v0.y*rh[v]);
      }
    }
    so0[tk*32+ep] = packf16(o0a, o0b);
#pragma unroll
    for (int v = 0; v < 3; ++v) so1[(v*TW+tk)*32+ep] = packf16(o1a[v], o1b[v]);
  }
  __syncthreads();

  // ---- phase 6: out-proj + residual (channel-pair per thread) ----
  {
    int e2 = tid & 31, grp = tid >> 5;
    u32 wA[32], wB[32];
#pragma unroll 8
    for (int c = 0; c < 32; ++c) { wA[c] = po0[c*64 + 2*e2]; wB[c] = po0[c*64 + 2*e2 + 1]; }
    for (int tk = grp; tk < TW; tk += 8) {
      float a = dot32(so0 + tk*32, wA);
      float b = dot32(so0 + tk*32, wB);
      float2 r = unpk(f0p[(bbase + nsin + tk)*32 + e2]);
      sf0n[tk*64 + 2*e2]     = r.x + a;
      sf0n[tk*64 + 2*e2 + 1] = r.y + b;
    }
#pragma unroll 8
    for (int c = 0; c < 32; ++c) { wA[c] = po1[c*64 + 2*e2]; wB[c] = po1[c*64 + 2*e2 + 1]; }
    for (int i = grp; i < 3*TW; i += 8) {
      int v = i >> 4, tk = i & 15;
      float a = dot32(so1 + (v*TW+tk)*32, wA);
      float b = dot32(so1 + (v*TW+tk)*32, wB);
      float2 r = unpk(f1p[((bbase+nsin+tk)*3+v)*32 + e2]);
      sf1n[(v*TW+tk)*64 + 2*e2]   = r.x + a;
      sf1n[(v*TW+tk)*64 + 2*e2+1] = r.y + b;
    }
  }
  __syncthreads();

  // ---- phase 7: ff0 LN + pack g ----
  {
    int g = tid >> 3, ln = tid & 7;
    if (g < TW) {
      float vv[8], s = 0.f, s2 = 0.f;
      const float* r = sf0n + g*64 + ln*8;
#pragma unroll
      for (int i = 0; i < 8; ++i) { float x = r[i]; vv[i] = x; s += x; s2 += x*x; }
#pragma unroll
      for (int m = 1; m < 8; m <<= 1) { s += __shfl_xor(s, m, 64); s2 += __shfl_xor(s2, m, 64); }
      float mu = s*(1.f/64.f);
      float ri = rsqrtf(fmaxf(s2*(1.f/64.f)-mu*mu, 0.f) + EPSF);
#pragma unroll
      for (int i = 0; i < 4; ++i)
        sgf[g*32 + ln*4 + i] = packf16((vv[2*i]-mu)*ri, (vv[2*i+1]-mu)*ri);
    }
  }
  __syncthreads();

  // ---- phase 8: ff0 hidden (64->256) + silu ----
  {
    int j = tid;
    u32 w[32];
#pragma unroll 8
    for (int c = 0; c < 32; ++c) w[c] = pa[c*256+j];
#pragma unroll 2
    for (int tk = 0; tk < TW; ++tk) {
      float acc = dot32(sgf + tk*32, w);
      sh[tk*256+j] = f16b(acc / (1.f + expf(-acc)));
    }
  }
  __syncthreads();

  // ---- phase 9: ff0 out (256->64) + residual + write f0p ----
  {
    int e2 = tid & 31, grp = tid >> 5;
    float aA[2] = {0.f,0.f}, aB[2] = {0.f,0.f};
    u32 wA[32], wB[32];
    for (int ch = 0; ch < 4; ++ch) {
#pragma unroll 8
      for (int c = 0; c < 32; ++c) { wA[c] = pb[(ch*32+c)*64 + 2*e2]; wB[c] = pb[(ch*32+c)*64 + 2*e2+1]; }
#pragma unroll
      for (int t = 0; t < 2; ++t) {
        int tk = grp + t*8;
        const u32* hp = (const u32*)sh + tk*128 + ch*32;
        aA[t] += dot32(hp, wA);
        aB[t] += dot32(hp, wB);
      }
    }
#pragma unroll
    for (int t = 0; t < 2; ++t) {
      int tk = grp + t*8;
      f0p[(bbase+nsin+tk)*32 + e2] = packf16(sf0n[tk*64+2*e2] + aA[t], sf0n[tk*64+2*e2+1] + aB[t]);
    }
  }
  // ---- phase 10: ff1 vnorm + pack (LDS regions disjoint from phase 9) ----
  {
    int g = tid >> 3, ln = tid & 7;
    if (g < TW) {
      float vv[24], ss = 0.f;
#pragma unroll
      for (int v = 0; v < 3; ++v) {
        const float* r = sf1n + (v*TW+g)*64 + ln*8;
#pragma unroll
        for (int i = 0; i < 8; ++i) { float x = r[i]; vv[v*8+i] = x; ss += x*x; }
      }
#pragma unroll
      for (int m = 1; m < 8; m <<= 1) ss += __shfl_xor(ss, m, 64);
      float vs = rsqrtf(ss*(1.f/64.f) + EPSF);
#pragma unroll
      for (int v = 0; v < 3; ++v)
#pragma unroll
        for (int i = 0; i < 4; ++i)
          sg1f[(v*TW+g)*32 + ln*4 + i] = packf16(vv[v*8+2*i]*vs, vv[v*8+2*i+1]*vs);
    }
  }
  __syncthreads();

  // ---- phase 11: ff1 out (64->64) + residual + write f1p ----
  {
    int e2 = tid & 31, grp = tid >> 5;
    u32 wA[32], wB[32];
#pragma unroll 8
    for (int c = 0; c < 32; ++c) { wA[c] = pf1w[c*64 + 2*e2]; wB[c] = pf1w[c*64 + 2*e2+1]; }
    for (int i = grp; i < 3*TW; i += 8) {
      int v = i >> 4, tk = i & 15;
      float a = dot32(sg1f + (v*TW+tk)*32, wA);
      float b = dot32(sg1f + (v*TW+tk)*32, wB);
      f1p[((bbase+nsin+tk)*3+v)*32 + e2] =
        packf16(sf1n[(v*TW+tk)*64+2*e2] + a, sf1n[(v*TW+tk)*64+2*e2+1] + b);
    }
  }
}

// ---------- final score ----------
__global__ __launch_bounds__(256) void k_final(const u32* f1p, const float* wout, const float* bout, float* out) {
  int tok = blockIdx.x*4 + (threadIdx.x >> 6);
  int lane = threadIdx.x & 63;
  float p[3];
#pragma unroll
  for (int v = 0; v < 3; ++v) {
    float2 pr = unpk(f1p[(tok*3+v)*32 + (lane>>1)]);
    float x = ((lane & 1) ? pr.y : pr.x) * wout[v*64 + lane];
#pragma unroll
    for (int m = 1; m < 64; m <<= 1) x += __shfl_xor(x, m, 64);
    p[v] = x;
  }
  if (lane < 3) out[tok*3 + lane] = p[lane] + bout[lane];
}

extern "C" void kernel_launch(void* const* d_in, const int* in_sizes, int n_in,
                              void* d_out, int out_size, void* d_ws, size_t ws_size,
                              hipStream_t stream) {
  float* out = (float*)d_out;
  static const int exp23[23] = {196608,196608,8,32768,32768,16384,128,7808,61,64,
                                16384,16384,16384,16384,16384,16384,16384,16384,
                                65536,65536,16384,192,3};
  bool ok23 = (n_in == 23), ok22 = (n_in == 22);
  int bad = -1;
  if (ok23) {
    for (int i = 0; i < 23; ++i) if (in_sizes[i] != exp23[i]) { ok23 = false; bad = i; break; }
  }
  if (!ok23 && ok22) {
    for (int i = 0; i < 22; ++i) {
      int want = (i == 0) ? exp23[0] : exp23[i+1];
      if (in_sizes[i] != want) { ok22 = false; if (bad < 0) bad = i; break; }
    }
  } else ok22 = false;
  if (!ok23 && !ok22) {
    k_const<<<768, 256, 0, stream>>>(out, (float)(3000 + (bad < 0 ? 100 + n_in : bad)));
    return;
  }
  int sh = ok23 ? 0 : -1;
  const int* nbr = (const int*)d_in[3 + sh];
  const float* F[20];
  F[0] = (const float*)d_in[0];
  F[1] = (const float*)d_in[2 + sh];
  for (int j = 0; j < 18; ++j) F[2 + j] = (const float*)d_in[5 + sh + j];

  char* ws = (char*)d_ws;
  u32*   W16  = (u32*)ws;                         // 557056 B
  float* te2  = (float*)(ws + 557056);            // 2048 B
  float* rhat = (float*)(ws + 559104);            // 3145728 B
  u32*   f0p  = (u32*)(ws + 3704832);             // BN*32*4 = 8388608 B
  u32*   f1p  = (u32*)(ws + 12093440);            // BN*96*4 = 25165824 B -> end ~37.3 MB

  WSrc s;
  s.m[0]=F[7]; s.m[1]=F[8]; s.m[2]=F[9]; s.m[3]=F[10]; s.m[4]=F[11]; s.m[5]=F[12];
  s.m[6]=F[13]; s.m[7]=F[14]; s.m[8]=F[17]; s.m[9]=F[15]; s.m[10]=F[16];

  k_prep<<<544, 256, 0, stream>>>(s, W16);
  k_te<<<1, 128, 0, stream>>>(F[1], F[2], F[3], F[4], F[5], te2);
  k_init<<<BN/8, 256, 0, stream>>>(F[0], F[6], nbr, te2, f0p, f1p, rhat);
  for (int l = 0; l < LL; ++l)
    k_layer<<<BN/TW, 256, 0, stream>>>(W16, l, nbr, rhat, f0p, f1p);
  k_final<<<BN/4, 256, 0, stream>>>(f1p, F[18], F[19], out);
}

// Round 10
// 2715.948 us; speedup vs baseline: 1.0015x; 1.0015x over previous
//
#include <hip/hip_runtime.h>

#define BB 8
#define NN 8192
#define RR 2048
#define KK 4
#define LL 4
#define TC 61
#define EPSF 1e-6f
#define BN (BB*NN)
#define OUTN (BN*3)
#define TW 16
#define PP 20

typedef unsigned short u16;
typedef unsigned int u32;
typedef _Float16 h2f __attribute__((ext_vector_type(2)));

__device__ __forceinline__ float fd2(u32 a, u32 b, float acc) {
#if __has_builtin(__builtin_amdgcn_fdot2)
  return __builtin_amdgcn_fdot2(__builtin_bit_cast(h2f, a), __builtin_bit_cast(h2f, b), acc, false);
#else
  h2f A = __builtin_bit_cast(h2f, a), B = __builtin_bit_cast(h2f, b);
  return acc + (float)A.x * (float)B.x + (float)A.y * (float)B.y;
#endif
}
__device__ __forceinline__ float dot32(const u32* g, const u32* w) {
  float a0=0.f, a1=0.f, a2=0.f, a3=0.f;
#pragma unroll
  for (int c = 0; c < 32; c += 4) {
    a0 = fd2(g[c+0], w[c+0], a0);
    a1 = fd2(g[c+1], w[c+1], a1);
    a2 = fd2(g[c+2], w[c+2], a2);
    a3 = fd2(g[c+3], w[c+3], a3);
  }
  return (a0+a1)+(a2+a3);
}
__device__ __forceinline__ u32 packf16(float a, float b) {
  h2f h; h.x = (_Float16)a; h.y = (_Float16)b; return __builtin_bit_cast(u32, h);
}
__device__ __forceinline__ u16 f16b(float a) {
  _Float16 h = (_Float16)a; return __builtin_bit_cast(u16, h);
}
__device__ __forceinline__ float2 unpk(u32 a) {
  h2f h = __builtin_bit_cast(h2f, a); return make_float2((float)h.x, (float)h.y);
}
__device__ __forceinline__ int kmax_of(int n) {
  int aatom = n & 3, rres = n >> 2;
  return (aatom==0) ? (rres==0 ? 2 : 3)
       : (aatom==1) ? 3
       : (aatom==2) ? (rres==RR-1 ? 3 : 4) : 2;
}

__global__ __launch_bounds__(256) void k_const(float* out, float v) {
  int i = blockIdx.x*256 + threadIdx.x;
  if (i < OUTN) out[i] = v;
}

// ---------- weight f16 pre-pack ----------
struct WSrc { const float* m[11]; };
__global__ __launch_bounds__(256) void k_prep(WSrc s, u32* W16) {
  int i = blockIdx.x*256 + threadIdx.x;   // 139264 items
  if (i < 73728) {                        // 9 matrices [64 x 64] per layer, pack over dim0
    int m = i >> 13, rr = i & 8191, l = rr >> 11, r2 = rr & 2047;
    int c2 = r2 >> 6, col = r2 & 63;
    const float* src = s.m[m] + l*4096;
    W16[i] = packf16(src[(2*c2)*64 + col], src[(2*c2+1)*64 + col]);
  } else if (i < 106496) {                // ffa [64 x 256], pack over c
    int j2 = i - 73728; int l = j2 >> 13, r2 = j2 & 8191;
    int c2 = r2 >> 8, j = r2 & 255;
    const float* src = s.m[9] + l*16384;
    W16[i] = packf16(src[(2*c2)*256 + j], src[(2*c2+1)*256 + j]);
  } else {                                // ffb [256 x 64], pack over j
    int j2 = i - 106496; int l = j2 >> 13, r2 = j2 & 8191;
    int jp = r2 >> 6, e = r2 & 63;
    const float* src = s.m[10] + l*16384;
    W16[i] = packf16(src[(2*jp)*64 + e], src[(2*jp+1)*64 + e]);
  }
}

// ---------- time embedding MLP ----------
__global__ __launch_bounds__(128) void k_te(const float* t, const float* w1, const float* b1,
                                            const float* w2, const float* b2, float* te2) {
  __shared__ float s0[128], s1[128];
  int j = threadIdx.x;
  for (int b = 0; b < BB; ++b) {
    float tv = t[b];
    int i = j & 63;
    float fr = expf(-9.210340371976184f * (float)i * (1.0f/64.0f));
    float em = tv * fr;
    s0[j] = (j < 64) ? sinf(em) : cosf(em);
    __syncthreads();
    float acc = b1[j];
    for (int i2 = 0; i2 < 128; ++i2) acc += s0[i2] * w1[i2*128 + j];
    s1[j] = acc / (1.f + expf(-acc));
    __syncthreads();
    if (j < TC) {
      float a2 = b2[j];
      for (int i2 = 0; i2 < 128; ++i2) a2 += s1[i2] * w2[i2*TC + j];
      te2[b*TC + j] = a2;
    }
    __syncthreads();
  }
}

// ---------- init f0p/f1p (packed f16 pairs) + rhat ----------
__global__ __launch_bounds__(256) void k_init(const float* x, const float* win1, const int* nbr,
                                              const float* te2, u32* f0p, u32* f1p, float* rhat) {
  int tok = blockIdx.x*8 + (threadIdx.x >> 5);
  int c2 = threadIdx.x & 31;
  int b = tok >> 13, n = tok & (NN-1);
  float x0 = x[tok*3+0], x1 = x[tok*3+1], x2 = x[tok*3+2];
  int ca = 2*c2, cb = 2*c2+1;
  float va = (ca < TC) ? te2[b*TC + ca] : (ca == 61 ? x0 : (ca == 62 ? x1 : x2));
  float vb = (cb < TC) ? te2[b*TC + cb] : (cb == 61 ? x0 : (cb == 62 ? x1 : x2));
  f0p[tok*32 + c2] = packf16(va, vb);
  float wa = win1[ca], wb = win1[cb];
  f1p[(tok*3+0)*32 + c2] = packf16(x0*wa, x0*wb);
  f1p[(tok*3+1)*32 + c2] = packf16(x1*wa, x1*wb);
  f1p[(tok*3+2)*32 + c2] = packf16(x2*wa, x2*wb);
  if (c2 < KK) {
    int tj = b*NN + nbr[n*KK + c2];
    float rx = x[tj*3+0] - x0, ry = x[tj*3+1] - x1, rz = x[tj*3+2] - x2;
    float ir = rsqrtf(rx*rx + ry*ry + rz*rz + EPSF);
    rhat[(tok*KK+c2)*3 + 0] = rx * ir;
    rhat[(tok*KK+c2)*3 + 1] = ry * ir;
    rhat[(tok*KK+c2)*3 + 2] = rz * ir;
  }
}

// ---------- fused layer (double-buffered residual: read fin*, write fout*) ----------
__global__ __launch_bounds__(256, 4) void k_layer(const u32* W16, int l,
    const int* nbr, const float* rhat,
    const u32* fin0, const u32* fin1, u32* fout0, u32* fout1) {
  __shared__ __align__(16) char SB[40960];
  u32* sg0 = (u32*)(SB);             // 20*32 u32 = 2560
  u32* sg1 = (u32*)(SB + 2560);      // 3*20*32 = 7680
  u16* sk0 = (u16*)(SB + 10240);     // 20*64 u16 = 2560
  u16* sv0 = (u16*)(SB + 12800);     // 2560
  u16* sk1 = (u16*)(SB + 15360);     // 3*20*64 = 7680
  u16* sv1 = (u16*)(SB + 23040);     // 7680
  u16* sq0 = (u16*)(SB + 30720);     // 16*64 = 2048
  u16* sq1 = (u16*)(SB + 32768);     // 3*16*64 = 6144
  float* srh = (float*)(SB + 38912); // 16*12 f32 = 768
  float* sa  = (float*)(SB + 39680); // 16*16 f32 = 1024
  int*  spk  = (int*)(SB + 40704);   // 16*4 = 256  -> total 40960
  // phase aliases (lifetimes disjoint, sync-separated)
  u32* so0   = (u32*)(SB);           // 16*32 (over sg0)
  u32* so1   = (u32*)(SB + 2560);    // 3*16*32 (over sg1)
  float* sf0n = (float*)(SB + 10240);// 16*64 f32 (over sk0/sv0)
  float* sf1n = (float*)(SB + 15360);// 3*16*64 f32 (over sk1/sv1)
  u32* sgf   = (u32*)(SB);           // (over so0)
  u32* sg1f  = (u32*)(SB + 2560);    // (over so1)
  u16* sh    = (u16*)(SB + 30720);   // 16*256 u16 (over sq0+sq1)

  const int tid = threadIdx.x;
  const int gb = blockIdx.x * TW;   // linear mapping (R8-proven)
  const int nsin = gb & (NN-1);
  const int bbase = gb - nsin;

  const u32 *pq0 = W16 + 0*8192 + l*2048, *pk0w = W16 + 1*8192 + l*2048, *pv0w = W16 + 2*8192 + l*2048;
  const u32 *pq1 = W16 + 3*8192 + l*2048, *pk1w = W16 + 4*8192 + l*2048, *pv1w = W16 + 5*8192 + l*2048;
  const u32 *po0 = W16 + 6*8192 + l*2048, *po1 = W16 + 7*8192 + l*2048, *pf1w = W16 + 8*8192 + l*2048;
  const u32 *pa = W16 + 73728 + l*8192, *pb = W16 + 106496 + l*8192;

  // ---- phase 1: LN/vnorm for PP tokens (8-lane groups), pack f16; stage rhat, nbr ----
  {
    int g = tid >> 3, ln = tid & 7;
    if (g < PP) {
      int p = g;
      int nl = nsin + p - 2; nl = nl < 0 ? 0 : (nl > NN-1 ? NN-1 : nl);
      int tok = bbase + nl;
      uint4 A0 = *((const uint4*)(fin0 + tok*32 + ln*4));
      float v0[8];
      { float2 t0=unpk(A0.x), t1=unpk(A0.y), t2=unpk(A0.z), t3=unpk(A0.w);
        v0[0]=t0.x; v0[1]=t0.y; v0[2]=t1.x; v0[3]=t1.y; v0[4]=t2.x; v0[5]=t2.y; v0[6]=t3.x; v0[7]=t3.y; }
      float s = 0.f, s2 = 0.f, ss = 0.f;
#pragma unroll
      for (int i = 0; i < 8; ++i) { s += v0[i]; s2 += v0[i]*v0[i]; }
      float v1[24];
#pragma unroll
      for (int v = 0; v < 3; ++v) {
        uint4 A1 = *((const uint4*)(fin1 + (tok*3+v)*32 + ln*4));
        float2 t0=unpk(A1.x), t1=unpk(A1.y), t2=unpk(A1.z), t3=unpk(A1.w);
        v1[v*8+0]=t0.x; v1[v*8+1]=t0.y; v1[v*8+2]=t1.x; v1[v*8+3]=t1.y;
        v1[v*8+4]=t2.x; v1[v*8+5]=t2.y; v1[v*8+6]=t3.x; v1[v*8+7]=t3.y;
#pragma unroll
        for (int i = 0; i < 8; ++i) ss += v1[v*8+i]*v1[v*8+i];
      }
#pragma unroll
      for (int m = 1; m < 8; m <<= 1) {
        s  += __shfl_xor(s,  m, 64);
        s2 += __shfl_xor(s2, m, 64);
        ss += __shfl_xor(ss, m, 64);
      }
      float mu = s * (1.f/64.f);
      float ri = rsqrtf(fmaxf(s2*(1.f/64.f) - mu*mu, 0.f) + EPSF);
      float vs = rsqrtf(ss*(1.f/64.f) + EPSF);
#pragma unroll
      for (int i = 0; i < 4; ++i)
        sg0[p*32 + ln*4 + i] = packf16((v0[2*i]-mu)*ri, (v0[2*i+1]-mu)*ri);
#pragma unroll
      for (int v = 0; v < 3; ++v)
#pragma unroll
        for (int i = 0; i < 4; ++i)
          sg1[(v*PP+p)*32 + ln*4 + i] = packf16(v1[v*8+2*i]*vs, v1[v*8+2*i+1]*vs);
    }
    if (tid < 192) { int tk = tid/12; srh[tid] = rhat[(gb+tk)*12 + (tid - tk*12)]; }
    if (tid < 64) {
      int tk = tid >> 2, k = tid & 3;
      int pv = nbr[(nsin+tk)*4 + k] - nsin + 2;
      spk[tid] = pv < 0 ? 0 : (pv > PP-1 ? PP-1 : pv);
    }
  }
  __syncthreads();

  // ---- phase 2: QKV projections (weight column in regs) ----
  {
    int e = tid & 63, grp = tid >> 6;
    u32 w[32];
#pragma unroll 8
    for (int c = 0; c < 32; ++c) w[c] = pq0[c*64+e];
    for (int tk = grp; tk < TW; tk += 4)
      sq0[tk*64+e] = f16b(dot32(sg0 + (tk+2)*32, w));
#pragma unroll 8
    for (int c = 0; c < 32; ++c) w[c] = pk0w[c*64+e];
    for (int p = grp; p < PP; p += 4)
      sk0[p*64+e] = f16b(dot32(sg0 + p*32, w));
#pragma unroll 8
    for (int c = 0; c < 32; ++c) w[c] = pv0w[c*64+e];
    for (int p = grp; p < PP; p += 4)
      sv0[p*64+e] = f16b(dot32(sg0 + p*32, w));
#pragma unroll 8
    for (int c = 0; c < 32; ++c) w[c] = pq1[c*64+e];
    for (int i = grp; i < 3*TW; i += 4) {
      int v = i >> 4, tk = i & 15;
      sq1[(v*TW+tk)*64+e] = f16b(dot32(sg1 + (v*PP + tk+2)*32, w));
    }
#pragma unroll 8
    for (int c = 0; c < 32; ++c) w[c] = pk1w[c*64+e];
    for (int v = 0; v < 3; ++v)
      for (int p = grp; p < PP; p += 4)
        sk1[(v*PP+p)*64+e] = f16b(dot32(sg1 + (v*PP + p)*32, w));
#pragma unroll 8
    for (int c = 0; c < 32; ++c) w[c] = pv1w[c*64+e];
    for (int v = 0; v < 3; ++v)
      for (int p = grp; p < PP; p += 4)
        sv1[(v*PP+p)*64+e] = f16b(dot32(sg1 + (v*PP + p)*32, w));
  }
  __syncthreads();

  // ---- phase 3: QK^T logits ----
  {
    int it = tid;
    int tk = it >> 4, h = (it >> 2) & 3, k = it & 3;
    int pk = spk[tk*4+k];
    const u32* qp = (const u32*)sq0 + tk*32 + h*8;
    const u32* kp = (const u32*)sk0 + pk*32 + h*8;
    float acc0 = 0.f, acc1 = 0.f;
#pragma unroll
    for (int d = 0; d < 8; d += 2) {
      acc0 = fd2(qp[d],   kp[d],   acc0);
      acc1 = fd2(qp[d+1], kp[d+1], acc1);
    }
#pragma unroll
    for (int v = 0; v < 3; ++v) {
      const u32* q1p = (const u32*)sq1 + (v*TW+tk)*32 + h*8;
      const u32* k1p = (const u32*)sk1 + (v*PP+pk)*32 + h*8;
#pragma unroll
      for (int d = 0; d < 8; d += 2) {
        acc0 = fd2(q1p[d],   k1p[d],   acc0);
        acc1 = fd2(q1p[d+1], k1p[d+1], acc1);
      }
    }
    sa[it] = (acc0 + acc1) * 0.25f;
  }
  __syncthreads();

  // ---- phase 4: softmax ----
  if (tid < 64) {
    int tk = tid >> 2, h = tid & 3;
    int km = kmax_of(nsin + tk);
    float* row = sa + tk*16 + h*4;
    float mx = -1e30f;
    for (int k = 0; k < km; ++k) mx = fmaxf(mx, row[k]);
    float s = 0.f, aw[4];
#pragma unroll
    for (int k = 0; k < 4; ++k) { aw[k] = (k < km) ? expf(row[k]-mx) : 0.f; s += aw[k]; }
    float inv = 1.f / s;
#pragma unroll
    for (int k = 0; k < 4; ++k) row[k] = aw[k]*inv;
  }
  __syncthreads();

  // ---- phase 5: AV ----
  for (int it = tid; it < TW*32; it += 256) {
    int tk = it >> 5, ep = it & 31, h = ep >> 3;
    const float* arow = sa + tk*16 + h*4;
    float o0a=0,o0b=0,o1a[3]={0,0,0},o1b[3]={0,0,0};
#pragma unroll
    for (int k = 0; k < 4; ++k) {
      float a = arow[k];
      int pk = spk[tk*4+k];
      float2 v0 = unpk(((const u32*)sv0)[pk*32+ep]);
      float vx[3], vy[3];
#pragma unroll
      for (int v = 0; v < 3; ++v) {
        float2 t = unpk(((const u32*)sv1)[(v*PP+pk)*32+ep]);
        vx[v]=t.x; vy[v]=t.y;
      }
      const float* rh = srh + tk*12 + k*3;
      float vda = vx[0]*rh[0]+vx[1]*rh[1]+vx[2]*rh[2];
      float vdb = vy[0]*rh[0]+vy[1]*rh[1]+vy[2]*rh[2];
      o0a += a*(v0.x + vda); o0b += a*(v0.y + vdb);
#pragma unroll
      for (int v = 0; v < 3; ++v) {
        o1a[v] += a*(vx[v] + v0.x*rh[v]);
        o1b[v] += a*(vy[v] + v0.y*rh[v]);
      }
    }
    so0[tk*32+ep] = packf16(o0a, o0b);
#pragma unroll
    for (int v = 0; v < 3; ++v) so1[(v*TW+tk)*32+ep] = packf16(o1a[v], o1b[v]);
  }
  __syncthreads();

  // ---- phase 6: out-proj + residual (channel-pair per thread, residual from fin) ----
  {
    int e2 = tid & 31, grp = tid >> 5;
    u32 wA[32], wB[32];
#pragma unroll 8
    for (int c = 0; c < 32; ++c) { wA[c] = po0[c*64 + 2*e2]; wB[c] = po0[c*64 + 2*e2 + 1]; }
    for (int tk = grp; tk < TW; tk += 8) {
      float a = dot32(so0 + tk*32, wA);
      float b = dot32(so0 + tk*32, wB);
      float2 r = unpk(fin0[(bbase + nsin + tk)*32 + e2]);
      sf0n[tk*64 + 2*e2]     = r.x + a;
      sf0n[tk*64 + 2*e2 + 1] = r.y + b;
    }
#pragma unroll 8
    for (int c = 0; c < 32; ++c) { wA[c] = po1[c*64 + 2*e2]; wB[c] = po1[c*64 + 2*e2 + 1]; }
    for (int i = grp; i < 3*TW; i += 8) {
      int v = i >> 4, tk = i & 15;
      float a = dot32(so1 + (v*TW+tk)*32, wA);
      float b = dot32(so1 + (v*TW+tk)*32, wB);
      float2 r = unpk(fin1[((bbase+nsin+tk)*3+v)*32 + e2]);
      sf1n[(v*TW+tk)*64 + 2*e2]   = r.x + a;
      sf1n[(v*TW+tk)*64 + 2*e2+1] = r.y + b;
    }
  }
  __syncthreads();

  // ---- phase 7: ff0 LN + pack g ----
  {
    int g = tid >> 3, ln = tid & 7;
    if (g < TW) {
      float vv[8], s = 0.f, s2 = 0.f;
      const float* r = sf0n + g*64 + ln*8;
#pragma unroll
      for (int i = 0; i < 8; ++i) { float x = r[i]; vv[i] = x; s += x; s2 += x*x; }
#pragma unroll
      for (int m = 1; m < 8; m <<= 1) { s += __shfl_xor(s, m, 64); s2 += __shfl_xor(s2, m, 64); }
      float mu = s*(1.f/64.f);
      float ri = rsqrtf(fmaxf(s2*(1.f/64.f)-mu*mu, 0.f) + EPSF);
#pragma unroll
      for (int i = 0; i < 4; ++i)
        sgf[g*32 + ln*4 + i] = packf16((vv[2*i]-mu)*ri, (vv[2*i+1]-mu)*ri);
    }
  }
  __syncthreads();

  // ---- phase 8: ff0 hidden (64->256) + silu ----
  {
    int j = tid;
    u32 w[32];
#pragma unroll 8
    for (int c = 0; c < 32; ++c) w[c] = pa[c*256+j];
#pragma unroll 2
    for (int tk = 0; tk < TW; ++tk) {
      float acc = dot32(sgf + tk*32, w);
      sh[tk*256+j] = f16b(acc / (1.f + expf(-acc)));
    }
  }
  __syncthreads();

  // ---- phase 9: ff0 out (256->64) + residual + write fout0 ----
  {
    int e2 = tid & 31, grp = tid >> 5;
    float aA[2] = {0.f,0.f}, aB[2] = {0.f,0.f};
    u32 wA[32], wB[32];
    for (int ch = 0; ch < 4; ++ch) {
#pragma unroll 8
      for (int c = 0; c < 32; ++c) { wA[c] = pb[(ch*32+c)*64 + 2*e2]; wB[c] = pb[(ch*32+c)*64 + 2*e2+1]; }
#pragma unroll
      for (int t = 0; t < 2; ++t) {
        int tk = grp + t*8;
        const u32* hp = (const u32*)sh + tk*128 + ch*32;
        aA[t] += dot32(hp, wA);
        aB[t] += dot32(hp, wB);
      }
    }
#pragma unroll
    for (int t = 0; t < 2; ++t) {
      int tk = grp + t*8;
      fout0[(bbase+nsin+tk)*32 + e2] = packf16(sf0n[tk*64+2*e2] + aA[t], sf0n[tk*64+2*e2+1] + aB[t]);
    }
  }
  // ---- phase 10: ff1 vnorm + pack (LDS regions disjoint from phase 9) ----
  {
    int g = tid >> 3, ln = tid & 7;
    if (g < TW) {
      float vv[24], ss = 0.f;
#pragma unroll
      for (int v = 0; v < 3; ++v) {
        const float* r = sf1n + (v*TW+g)*64 + ln*8;
#pragma unroll
        for (int i = 0; i < 8; ++i) { float x = r[i]; vv[v*8+i] = x; ss += x*x; }
      }
#pragma unroll
      for (int m = 1; m < 8; m <<= 1) ss += __shfl_xor(ss, m, 64);
      float vs = rsqrtf(ss*(1.f/64.f) + EPSF);
#pragma unroll
      for (int v = 0; v < 3; ++v)
#pragma unroll
        for (int i = 0; i < 4; ++i)
          sg1f[(v*TW+g)*32 + ln*4 + i] = packf16(vv[v*8+2*i]*vs, vv[v*8+2*i+1]*vs);
    }
  }
  __syncthreads();

  // ---- phase 11: ff1 out (64->64) + residual + write fout1 ----
  {
    int e2 = tid & 31, grp = tid >> 5;
    u32 wA[32], wB[32];
#pragma unroll 8
    for (int c = 0; c < 32; ++c) { wA[c] = pf1w[c*64 + 2*e2]; wB[c] = pf1w[c*64 + 2*e2+1]; }
    for (int i = grp; i < 3*TW; i += 8) {
      int v = i >> 4, tk = i & 15;
      float a = dot32(sg1f + (v*TW+tk)*32, wA);
      float b = dot32(sg1f + (v*TW+tk)*32, wB);
      fout1[((bbase+nsin+tk)*3+v)*32 + e2] =
        packf16(sf1n[(v*TW+tk)*64+2*e2] + a, sf1n[(v*TW+tk)*64+2*e2+1] + b);
    }
  }
}

// ---------- final score ----------
__global__ __launch_bounds__(256) void k_final(const u32* f1p, const float* wout, const float* bout, float* out) {
  int tok = blockIdx.x*4 + (threadIdx.x >> 6);
  int lane = threadIdx.x & 63;
  float p[3];
#pragma unroll
  for (int v = 0; v < 3; ++v) {
    float2 pr = unpk(f1p[(tok*3+v)*32 + (lane>>1)]);
    float x = ((lane & 1) ? pr.y : pr.x) * wout[v*64 + lane];
#pragma unroll
    for (int m = 1; m < 64; m <<= 1) x += __shfl_xor(x, m, 64);
    p[v] = x;
  }
  if (lane < 3) out[tok*3 + lane] = p[lane] + bout[lane];
}

extern "C" void kernel_launch(void* const* d_in, const int* in_sizes, int n_in,
                              void* d_out, int out_size, void* d_ws, size_t ws_size,
                              hipStream_t stream) {
  float* out = (float*)d_out;
  static const int exp23[23] = {196608,196608,8,32768,32768,16384,128,7808,61,64,
                                16384,16384,16384,16384,16384,16384,16384,16384,
                                65536,65536,16384,192,3};
  bool ok23 = (n_in == 23), ok22 = (n_in == 22);
  int bad = -1;
  if (ok23) {
    for (int i = 0; i < 23; ++i) if (in_sizes[i] != exp23[i]) { ok23 = false; bad = i; break; }
  }
  if (!ok23 && ok22) {
    for (int i = 0; i < 22; ++i) {
      int want = (i == 0) ? exp23[0] : exp23[i+1];
      if (in_sizes[i] != want) { ok22 = false; if (bad < 0) bad = i; break; }
    }
  } else ok22 = false;
  if (!ok23 && !ok22) {
    k_const<<<768, 256, 0, stream>>>(out, (float)(3000 + (bad < 0 ? 100 + n_in : bad)));
    return;
  }
  int sh = ok23 ? 0 : -1;
  const int* nbr = (const int*)d_in[3 + sh];
  const float* F[20];
  F[0] = (const float*)d_in[0];
  F[1] = (const float*)d_in[2 + sh];
  for (int j = 0; j < 18; ++j) F[2 + j] = (const float*)d_in[5 + sh + j];

  char* ws = (char*)d_ws;
  u32*   W16  = (u32*)ws;                          // 557056 B
  float* te2  = (float*)(ws + 557056);             // 2048 B
  float* rhat = (float*)(ws + 559104);             // 3145728 B
  u32*   f0A  = (u32*)(ws + 3704832);              // 8 MB
  u32*   f1A  = (u32*)(ws + 12093440);             // 24 MB
  u32*   f0B  = (u32*)(ws + 37259264);             // 8 MB
  u32*   f1B  = (u32*)(ws + 45647872);             // 24 MB -> end ~70.8 MB

  WSrc s;
  s.m[0]=F[7]; s.m[1]=F[8]; s.m[2]=F[9]; s.m[3]=F[10]; s.m[4]=F[11]; s.m[5]=F[12];
  s.m[6]=F[13]; s.m[7]=F[14]; s.m[8]=F[17]; s.m[9]=F[15]; s.m[10]=F[16];

  k_prep<<<544, 256, 0, stream>>>(s, W16);
  k_te<<<1, 128, 0, stream>>>(F[1], F[2], F[3], F[4], F[5], te2);
  k_init<<<BN/8, 256, 0, stream>>>(F[0], F[6], nbr, te2, f0A, f1A, rhat);
  // layers alternate A->B->A->B->A
  k_layer<<<BN/TW, 256, 0, stream>>>(W16, 0, nbr, rhat, f0A, f1A, f0B, f1B);
  k_layer<<<BN/TW, 256, 0, stream>>>(W16, 1, nbr, rhat, f0B, f1B, f0A, f1A);
  k_layer<<<BN/TW, 256, 0, stream>>>(W16, 2, nbr, rhat, f0A, f1A, f0B, f1B);
  k_layer<<<BN/TW, 256, 0, stream>>>(W16, 3, nbr, rhat, f0B, f1B, f0A, f1A);
  k_final<<<BN/4, 256, 0, stream>>>(f1A, F[18], F[19], out);
}

// Round 11
// 2026.062 us; speedup vs baseline: 1.3426x; 1.3405x over previous
//
#include <hip/hip_runtime.h>

#define BB 8
#define NN 8192
#define RR 2048
#define LL 4
#define TC 61
#define EPSF 1e-6f
#define BN (BB*NN)
#define OUTN (BN*3)
#define CH 32768   // tokens per chunk (2 chunks, split at batch boundary)

typedef unsigned short u16;
typedef unsigned int u32;
typedef _Float16 h2f __attribute__((ext_vector_type(2)));

__device__ __forceinline__ float fd2(u32 a, u32 b, float acc) {
#if __has_builtin(__builtin_amdgcn_fdot2)
  return __builtin_amdgcn_fdot2(__builtin_bit_cast(h2f, a), __builtin_bit_cast(h2f, b), acc, false);
#else
  h2f A = __builtin_bit_cast(h2f, a), B = __builtin_bit_cast(h2f, b);
  return acc + (float)A.x * (float)B.x + (float)A.y * (float)B.y;
#endif
}
__device__ __forceinline__ float dot32(const u32* g, const u32* w) {
  float a0=0.f, a1=0.f, a2=0.f, a3=0.f;
#pragma unroll
  for (int c = 0; c < 32; c += 4) {
    a0 = fd2(g[c+0], w[c+0], a0);
    a1 = fd2(g[c+1], w[c+1], a1);
    a2 = fd2(g[c+2], w[c+2], a2);
    a3 = fd2(g[c+3], w[c+3], a3);
  }
  return (a0+a1)+(a2+a3);
}
__device__ __forceinline__ u32 packf16(float a, float b) {
  h2f h; h.x = (_Float16)a; h.y = (_Float16)b; return __builtin_bit_cast(u32, h);
}
__device__ __forceinline__ u16 f16b(float a) {
  _Float16 h = (_Float16)a; return __builtin_bit_cast(u16, h);
}
__device__ __forceinline__ float f162f(u16 h) { return (float)__builtin_bit_cast(_Float16, h); }
__device__ __forceinline__ float2 unpk(u32 a) {
  h2f h = __builtin_bit_cast(h2f, a); return make_float2((float)h.x, (float)h.y);
}
__device__ __forceinline__ void up8(uint4 A, float* v) {
  float2 t0=unpk(A.x), t1=unpk(A.y), t2=unpk(A.z), t3=unpk(A.w);
  v[0]=t0.x; v[1]=t0.y; v[2]=t1.x; v[3]=t1.y; v[4]=t2.x; v[5]=t2.y; v[6]=t3.x; v[7]=t3.y;
}
__device__ __forceinline__ int kmax_of(int n) {
  int aatom = n & 3, rres = n >> 2;
  return (aatom==0) ? (rres==0 ? 2 : 3)
       : (aatom==1) ? 3
       : (aatom==2) ? (rres==RR-1 ? 3 : 4) : 2;
}

__global__ __launch_bounds__(256) void k_const(float* out, float v) {
  int i = blockIdx.x*256 + threadIdx.x;
  if (i < OUTN) out[i] = v;
}

// ---------- weight f16 pre-pack (pairs over input dim) ----------
struct WSrc { const float* m[11]; };
__global__ __launch_bounds__(256) void k_prep(WSrc s, u32* W16) {
  int i = blockIdx.x*256 + threadIdx.x;   // 139264 items
  if (i < 73728) {                        // 9 [64x64] mats: Wq0,Wk0,Wv0,Wq1,Wk1,Wv1,Wo0,Wo1,Wff1
    int m = i >> 13, rr = i & 8191, l = rr >> 11, r2 = rr & 2047;
    int c2 = r2 >> 6, col = r2 & 63;
    const float* src = s.m[m] + l*4096;
    W16[i] = packf16(src[(2*c2)*64 + col], src[(2*c2+1)*64 + col]);
  } else if (i < 106496) {                // ffa [64 x 256]
    int j2 = i - 73728; int l = j2 >> 13, r2 = j2 & 8191;
    int c2 = r2 >> 8, j = r2 & 255;
    const float* src = s.m[9] + l*16384;
    W16[i] = packf16(src[(2*c2)*256 + j], src[(2*c2+1)*256 + j]);
  } else {                                // ffb [256 x 64]
    int j2 = i - 106496; int l = j2 >> 13, r2 = j2 & 8191;
    int jp = r2 >> 6, e = r2 & 63;
    const float* src = s.m[10] + l*16384;
    W16[i] = packf16(src[(2*jp)*64 + e], src[(2*jp+1)*64 + e]);
  }
}

// ---------- time embedding MLP ----------
__global__ __launch_bounds__(128) void k_te(const float* t, const float* w1, const float* b1,
                                            const float* w2, const float* b2, float* te2) {
  __shared__ float s0[128], s1[128];
  int j = threadIdx.x;
  for (int b = 0; b < BB; ++b) {
    float tv = t[b];
    int i = j & 63;
    float fr = expf(-9.210340371976184f * (float)i * (1.0f/64.0f));
    float em = tv * fr;
    s0[j] = (j < 64) ? sinf(em) : cosf(em);
    __syncthreads();
    float acc = b1[j];
    for (int i2 = 0; i2 < 128; ++i2) acc += s0[i2] * w1[i2*128 + j];
    s1[j] = acc / (1.f + expf(-acc));
    __syncthreads();
    if (j < TC) {
      float a2 = b2[j];
      for (int i2 = 0; i2 < 128; ++i2) a2 += s1[i2] * w2[i2*TC + j];
      te2[b*TC + j] = a2;
    }
    __syncthreads();
  }
}

// ---------- init f0p/f1p (packed f16 pairs) + rhat (f16) ----------
__global__ __launch_bounds__(256) void k_init(const float* x, const float* win1, const int* nbr,
                                              const float* te2, u32* f0p, u32* f1p, u16* rhat) {
  int tok = blockIdx.x*8 + (threadIdx.x >> 5);
  int c2 = threadIdx.x & 31;
  int b = tok >> 13, n = tok & (NN-1);
  float x0 = x[tok*3+0], x1 = x[tok*3+1], x2 = x[tok*3+2];
  int ca = 2*c2, cb = 2*c2+1;
  float va = (ca < TC) ? te2[b*TC + ca] : (ca == 61 ? x0 : (ca == 62 ? x1 : x2));
  float vb = (cb < TC) ? te2[b*TC + cb] : (cb == 61 ? x0 : (cb == 62 ? x1 : x2));
  f0p[tok*32 + c2] = packf16(va, vb);
  float wa = win1[ca], wb = win1[cb];
  f1p[(tok*3+0)*32 + c2] = packf16(x0*wa, x0*wb);
  f1p[(tok*3+1)*32 + c2] = packf16(x1*wa, x1*wb);
  f1p[(tok*3+2)*32 + c2] = packf16(x2*wa, x2*wb);
  if (c2 < 4) {
    int tj = b*NN + nbr[n*4 + c2];
    float rx = x[tj*3+0] - x0, ry = x[tj*3+1] - x1, rz = x[tj*3+2] - x2;
    float ir = rsqrtf(rx*rx + ry*ry + rz*rz + EPSF);
    rhat[(tok*4+c2)*3 + 0] = f16b(rx * ir);
    rhat[(tok*4+c2)*3 + 1] = f16b(ry * ir);
    rhat[(tok*4+c2)*3 + 2] = f16b(rz * ir);
  }
}

// ---------- kA: LN/vnorm + 6 QKV projections (wave = 8 tokens) ----------
__global__ __launch_bounds__(256) void k_qkv(const u32* W16, int l,
    const u32* f0p, const u32* f1p, int tokb,
    u16* Q0, u16* K0, u16* V0, u16* Q1, u16* K1, u16* V1) {
  __shared__ u32 S[4096];            // 4 waves x 1024 u32
  int tid = threadIdx.x, wv = tid >> 6, lane = tid & 63;
  u32* sg0 = S + wv*1024;            // 8 tok x 32
  u32* sg1 = sg0 + 256;              // 3 x 8 x 32
  int tl8 = (blockIdx.x*4 + wv)*8;
  {
    int g8 = lane >> 3, ln = lane & 7;
    int gt = tokb + tl8 + g8;
    uint4 A0 = *(const uint4*)(f0p + (size_t)gt*32 + ln*4);
    float v0[8]; up8(A0, v0);
    float s=0.f, s2=0.f, ss=0.f;
#pragma unroll
    for (int i = 0; i < 8; ++i) { s += v0[i]; s2 += v0[i]*v0[i]; }
    float v1[24];
#pragma unroll
    for (int v = 0; v < 3; ++v) {
      uint4 A = *(const uint4*)(f1p + (size_t)(gt*3+v)*32 + ln*4);
      up8(A, v1 + v*8);
#pragma unroll
      for (int i = 0; i < 8; ++i) ss += v1[v*8+i]*v1[v*8+i];
    }
#pragma unroll
    for (int m = 1; m < 8; m <<= 1) {
      s += __shfl_xor(s, m, 64); s2 += __shfl_xor(s2, m, 64); ss += __shfl_xor(ss, m, 64);
    }
    float mu = s*(1.f/64.f);
    float ri = rsqrtf(fmaxf(s2*(1.f/64.f)-mu*mu, 0.f) + EPSF);
    float vs = rsqrtf(ss*(1.f/64.f) + EPSF);
#pragma unroll
    for (int i = 0; i < 4; ++i)
      sg0[g8*32 + ln*4 + i] = packf16((v0[2*i]-mu)*ri, (v0[2*i+1]-mu)*ri);
#pragma unroll
    for (int v = 0; v < 3; ++v)
#pragma unroll
      for (int i = 0; i < 4; ++i)
        sg1[(v*8+g8)*32 + ln*4 + i] = packf16(v1[v*8+2*i]*vs, v1[v*8+2*i+1]*vs);
  }
  __syncthreads();
  int e = lane;
  u32 w[32];
  const u32* mats0[3] = {W16 + 0*8192 + l*2048, W16 + 1*8192 + l*2048, W16 + 2*8192 + l*2048};
  u16* outs0[3] = {Q0, K0, V0};
#pragma unroll
  for (int m = 0; m < 3; ++m) {
    const u32* pm = mats0[m];
#pragma unroll 8
    for (int c = 0; c < 32; ++c) w[c] = pm[c*64+e];
#pragma unroll
    for (int t = 0; t < 8; ++t)
      outs0[m][(size_t)(tl8+t)*64 + e] = f16b(dot32(sg0 + t*32, w));
  }
  const u32* mats1[3] = {W16 + 3*8192 + l*2048, W16 + 4*8192 + l*2048, W16 + 5*8192 + l*2048};
  u16* outs1[3] = {Q1, K1, V1};
#pragma unroll
  for (int m = 0; m < 3; ++m) {
    const u32* pm = mats1[m];
#pragma unroll 8
    for (int c = 0; c < 32; ++c) w[c] = pm[c*64+e];
#pragma unroll
    for (int v = 0; v < 3; ++v)
#pragma unroll
      for (int t = 0; t < 8; ++t)
        outs1[m][(size_t)((tl8+t)*3+v)*64 + e] = f16b(dot32(sg1 + (v*8+t)*32, w));
  }
}

// ---------- kB: gather + attention (wave = 1 token, zero barriers) ----------
__global__ __launch_bounds__(256) void k_attn(const u16* Q0, const u16* K0, const u16* V0,
    const u16* Q1, const u16* K1, const u16* V1, const int* nbr, const u16* rhat,
    int tokb, u16* o0, u16* o1) {
  int tid = threadIdx.x, wv = tid >> 6, e = tid & 63;
  int tl = blockIdx.x*4 + wv;
  int gt = tokb + tl;
  int n = gt & (NN-1);
  int km = kmax_of(n);
  int base = gt - n - tokb;             // local batch base
  int tk[4];
#pragma unroll
  for (int k = 0; k < 4; ++k) tk[k] = nbr[n*4+k] + base;
  float q0 = f162f(Q0[(size_t)tl*64+e]);
  float q1[3];
#pragma unroll
  for (int v = 0; v < 3; ++v) q1[v] = f162f(Q1[(size_t)(tl*3+v)*64+e]);
  float k0r[4], v0r[4], k1r[4][3], v1r[4][3], rh[4][3];
#pragma unroll
  for (int k = 0; k < 4; ++k) {
    k0r[k] = f162f(K0[(size_t)tk[k]*64+e]);
    v0r[k] = f162f(V0[(size_t)tk[k]*64+e]);
#pragma unroll
    for (int v = 0; v < 3; ++v) {
      k1r[k][v] = f162f(K1[(size_t)(tk[k]*3+v)*64+e]);
      v1r[k][v] = f162f(V1[(size_t)(tk[k]*3+v)*64+e]);
      rh[k][v]  = f162f(rhat[(size_t)(gt*4+k)*3+v]);
    }
  }
  float p[4];
#pragma unroll
  for (int k = 0; k < 4; ++k)
    p[k] = q0*k0r[k] + q1[0]*k1r[k][0] + q1[1]*k1r[k][1] + q1[2]*k1r[k][2];
#pragma unroll
  for (int m = 1; m < 16; m <<= 1) {
#pragma unroll
    for (int k = 0; k < 4; ++k) p[k] += __shfl_xor(p[k], m, 64);
  }
  float mx = -1e30f;
#pragma unroll
  for (int k = 0; k < 4; ++k) { p[k] *= 0.25f; if (k < km) mx = fmaxf(mx, p[k]); }
  float aw[4], ssum = 0.f;
#pragma unroll
  for (int k = 0; k < 4; ++k) { aw[k] = (k < km) ? expf(p[k]-mx) : 0.f; ssum += aw[k]; }
  float inv = 1.f / ssum;
  float O0 = 0.f, O1[3] = {0.f,0.f,0.f};
#pragma unroll
  for (int k = 0; k < 4; ++k) {
    float a = aw[k]*inv;
    float vd = v1r[k][0]*rh[k][0] + v1r[k][1]*rh[k][1] + v1r[k][2]*rh[k][2];
    O0 += a*(v0r[k] + vd);
#pragma unroll
    for (int v = 0; v < 3; ++v) O1[v] += a*(v1r[k][v] + v0r[k]*rh[k][v]);
  }
  o0[(size_t)tl*64+e] = f16b(O0);
#pragma unroll
  for (int v = 0; v < 3; ++v) o1[(size_t)(tl*3+v)*64+e] = f16b(O1[v]);
}

// ---------- kCD: out-proj + residual + LN + ffa(silu) (wave = 8 tokens) ----------
__global__ __launch_bounds__(256) void k_od(const u32* W16, int l,
    const u16* o0, const u16* o1, const u32* f0p, const u32* f1p, int tokb,
    u16* f0mid, u16* f1mid, u16* hbuf) {
  __shared__ u32 S[5120];
  int tid = threadIdx.x, wv = tid >> 6, lane = tid & 63;
  u32* so0 = S + wv*1280; u32* so1 = so0 + 256; u32* sgf = so0 + 1024; // 256 u32 = 512 u16
  int tl8 = (blockIdx.x*4 + wv)*8;
  {
    int g8 = lane >> 3, ln = lane & 7;
    int tl = tl8 + g8;
    const u32* o0u = (const u32*)o0;
    *(uint4*)(so0 + g8*32 + ln*4) = *(const uint4*)(o0u + (size_t)tl*32 + ln*4);
    const u32* o1u = (const u32*)o1;
#pragma unroll
    for (int v = 0; v < 3; ++v)
      *(uint4*)(so1 + (v*8+g8)*32 + ln*4) = *(const uint4*)(o1u + (size_t)(tl*3+v)*32 + ln*4);
  }
  __syncthreads();
  int e = lane;
  const u32* po0 = W16 + 6*8192 + l*2048;
  const u32* po1 = W16 + 7*8192 + l*2048;
  const u32* pa  = W16 + 73728 + l*8192;
  u32 w[32];
#pragma unroll 8
  for (int c = 0; c < 32; ++c) w[c] = po0[c*64+e];
  float f0v[8];
#pragma unroll
  for (int t = 0; t < 8; ++t) {
    float2 r = unpk(f0p[(size_t)(tokb+tl8+t)*32 + (e>>1)]);
    f0v[t] = dot32(so0 + t*32, w) + ((e&1) ? r.y : r.x);
    f0mid[(size_t)(tl8+t)*64+e] = f16b(f0v[t]);
  }
  u16* gf16 = (u16*)sgf;
#pragma unroll
  for (int t = 0; t < 8; ++t) {
    float s = f0v[t], s2 = f0v[t]*f0v[t];
#pragma unroll
    for (int m = 1; m < 64; m <<= 1) { s += __shfl_xor(s, m, 64); s2 += __shfl_xor(s2, m, 64); }
    float mu = s*(1.f/64.f);
    float ri = rsqrtf(fmaxf(s2*(1.f/64.f)-mu*mu, 0.f) + EPSF);
    gf16[t*64+e] = f16b((f0v[t]-mu)*ri);
  }
#pragma unroll 8
  for (int c = 0; c < 32; ++c) w[c] = po1[c*64+e];
#pragma unroll
  for (int v = 0; v < 3; ++v)
#pragma unroll
    for (int t = 0; t < 8; ++t) {
      float2 r = unpk(f1p[(size_t)((tokb+tl8+t)*3+v)*32 + (e>>1)]);
      float val = dot32(so1 + (v*8+t)*32, w) + ((e&1) ? r.y : r.x);
      f1mid[(size_t)((tl8+t)*3+v)*64+e] = f16b(val);
    }
  __syncthreads();
#pragma unroll
  for (int s4 = 0; s4 < 4; ++s4) {
    int j = s4*64 + e;
#pragma unroll 8
    for (int c = 0; c < 32; ++c) w[c] = pa[c*256+j];
#pragma unroll
    for (int t = 0; t < 8; ++t) {
      float a = dot32(sgf + t*32, w);
      hbuf[(size_t)(tl8+t)*256 + j] = f16b(a / (1.f + expf(-a)));
    }
  }
}

// ---------- kEF: ffb + residual -> f0p ; vnorm + ff1 + residual -> f1p ----------
__global__ __launch_bounds__(256) void k_fb(const u32* W16, int l, const u16* hbuf,
    const u16* f0mid, const u16* f1mid, int tokb, u32* f0p, u32* f1p) {
  __shared__ u32 S[7168];
  int tid = threadIdx.x, wv = tid >> 6, lane = tid & 63;
  u32* sh = S + wv*1792; u32* sg1 = sh + 1024;
  int tl8 = (blockIdx.x*4 + wv)*8;
  const u32* hu = (const u32*)hbuf;
#pragma unroll
  for (int t = 0; t < 8; ++t) {
    uint2 d = *(const uint2*)(hu + (size_t)(tl8+t)*128 + lane*2);
    sh[t*128 + lane*2] = d.x; sh[t*128 + lane*2 + 1] = d.y;
  }
  {
    int g8 = lane >> 3, ln = lane & 7;
    int tl = tl8 + g8;
    const u32* fmu = (const u32*)f1mid;
    float v1[24]; float ss = 0.f;
#pragma unroll
    for (int v = 0; v < 3; ++v) {
      uint4 A = *(const uint4*)(fmu + (size_t)(tl*3+v)*32 + ln*4);
      up8(A, v1 + v*8);
#pragma unroll
      for (int i = 0; i < 8; ++i) ss += v1[v*8+i]*v1[v*8+i];
    }
#pragma unroll
    for (int m = 1; m < 8; m <<= 1) ss += __shfl_xor(ss, m, 64);
    float vs = rsqrtf(ss*(1.f/64.f) + EPSF);
#pragma unroll
    for (int v = 0; v < 3; ++v)
#pragma unroll
      for (int i = 0; i < 4; ++i)
        sg1[(v*8+g8)*32 + ln*4 + i] = packf16(v1[v*8+2*i]*vs, v1[v*8+2*i+1]*vs);
  }
  __syncthreads();
  int e = lane;
  const u32* pb   = W16 + 106496 + l*8192;
  const u32* pf1w = W16 + 8*8192 + l*2048;
  float acc[8] = {0,0,0,0,0,0,0,0};
  u32 w[32];
  for (int ch = 0; ch < 4; ++ch) {
#pragma unroll 8
    for (int c = 0; c < 32; ++c) w[c] = pb[(ch*32+c)*64+e];
#pragma unroll
    for (int t = 0; t < 8; ++t) acc[t] += dot32(sh + t*128 + ch*32, w);
  }
#pragma unroll
  for (int t = 0; t < 8; ++t) {
    float r = f162f(f0mid[(size_t)(tl8+t)*64+e]) + acc[t];
    float o = __shfl_xor(r, 1, 64);
    if (!(e&1)) f0p[(size_t)(tokb+tl8+t)*32 + (e>>1)] = packf16(r, o);
  }
#pragma unroll 8
  for (int c = 0; c < 32; ++c) w[c] = pf1w[c*64+e];
#pragma unroll
  for (int v = 0; v < 3; ++v)
#pragma unroll
    for (int t = 0; t < 8; ++t) {
      float r = dot32(sg1 + (v*8+t)*32, w) + f162f(f1mid[(size_t)((tl8+t)*3+v)*64+e]);
      float o = __shfl_xor(r, 1, 64);
      if (!(e&1)) f1p[(size_t)((tokb+tl8+t)*3+v)*32 + (e>>1)] = packf16(r, o);
    }
}

// ---------- final score ----------
__global__ __launch_bounds__(256) void k_final(const u32* f1p, const float* wout, const float* bout, float* out) {
  int tok = blockIdx.x*4 + (threadIdx.x >> 6);
  int lane = threadIdx.x & 63;
  float p[3];
#pragma unroll
  for (int v = 0; v < 3; ++v) {
    float2 pr = unpk(f1p[(size_t)(tok*3+v)*32 + (lane>>1)]);
    float x = ((lane & 1) ? pr.y : pr.x) * wout[v*64 + lane];
#pragma unroll
    for (int m = 1; m < 64; m <<= 1) x += __shfl_xor(x, m, 64);
    p[v] = x;
  }
  if (lane < 3) out[tok*3 + lane] = p[lane] + bout[lane];
}

extern "C" void kernel_launch(void* const* d_in, const int* in_sizes, int n_in,
                              void* d_out, int out_size, void* d_ws, size_t ws_size,
                              hipStream_t stream) {
  float* out = (float*)d_out;
  static const int exp23[23] = {196608,196608,8,32768,32768,16384,128,7808,61,64,
                                16384,16384,16384,16384,16384,16384,16384,16384,
                                65536,65536,16384,192,3};
  bool ok23 = (n_in == 23), ok22 = (n_in == 22);
  int bad = -1;
  if (ok23) {
    for (int i = 0; i < 23; ++i) if (in_sizes[i] != exp23[i]) { ok23 = false; bad = i; break; }
  }
  if (!ok23 && ok22) {
    for (int i = 0; i < 22; ++i) {
      int want = (i == 0) ? exp23[0] : exp23[i+1];
      if (in_sizes[i] != want) { ok22 = false; if (bad < 0) bad = i; break; }
    }
  } else ok22 = false;
  if (!ok23 && !ok22) {
    k_const<<<768, 256, 0, stream>>>(out, (float)(3000 + (bad < 0 ? 100 + n_in : bad)));
    return;
  }
  int sh = ok23 ? 0 : -1;
  const int* nbr = (const int*)d_in[3 + sh];
  const float* F[20];
  F[0] = (const float*)d_in[0];
  F[1] = (const float*)d_in[2 + sh];
  for (int j = 0; j < 18; ++j) F[2 + j] = (const float*)d_in[5 + sh + j];

  char* ws = (char*)d_ws;
  u32*   W16  = (u32*)ws;                           // 557,056 B
  float* te2  = (float*)(ws + 557056);              // 2,048 B
  u16*   rhat = (u16*)(ws + 559104);                // BN*12*2 = 1,572,864
  u32*   f0p  = (u32*)(ws + 2131968);               // 8,388,608
  u32*   f1p  = (u32*)(ws + 10520576);              // 25,165,824
  char*  cb   = ws + 35686400;                      // chunk area: 64 MB -> end 102,795,264
  u16* Q0 = (u16*)(cb + 0);
  u16* K0 = (u16*)(cb + 4194304);
  u16* V0 = (u16*)(cb + 8388608);
  u16* Q1 = (u16*)(cb + 12582912);
  u16* K1 = (u16*)(cb + 25165824);
  u16* V1 = (u16*)(cb + 37748736);
  u16* o0 = (u16*)(cb + 50331648);
  u16* o1 = (u16*)(cb + 54525952);
  // overlays (dead after k_attn):
  u16* hbuf  = Q1;            // 16 MB over Q1+K1
  u16* f0mid = V0;            // 4 MB
  u16* f1mid = V1;            // 12 MB

  WSrc s;
  s.m[0]=F[7]; s.m[1]=F[8]; s.m[2]=F[9]; s.m[3]=F[10]; s.m[4]=F[11]; s.m[5]=F[12];
  s.m[6]=F[13]; s.m[7]=F[14]; s.m[8]=F[17]; s.m[9]=F[15]; s.m[10]=F[16];

  k_prep<<<544, 256, 0, stream>>>(s, W16);
  k_te<<<1, 128, 0, stream>>>(F[1], F[2], F[3], F[4], F[5], te2);
  k_init<<<BN/8, 256, 0, stream>>>(F[0], F[6], nbr, te2, f0p, f1p, rhat);
  for (int c = 0; c < 2; ++c) {
    int tokb = c * CH;
    for (int l = 0; l < LL; ++l) {
      k_qkv<<<CH/32, 256, 0, stream>>>(W16, l, f0p, f1p, tokb, Q0, K0, V0, Q1, K1, V1);
      k_attn<<<CH/4, 256, 0, stream>>>(Q0, K0, V0, Q1, K1, V1, nbr, rhat, tokb, o0, o1);
      k_od<<<CH/32, 256, 0, stream>>>(W16, l, o0, o1, f0p, f1p, tokb, f0mid, f1mid, hbuf);
      k_fb<<<CH/32, 256, 0, stream>>>(W16, l, hbuf, f0mid, f1mid, tokb, f0p, f1p);
    }
  }
  k_final<<<BN/4, 256, 0, stream>>>(f1p, F[18], F[19], out);
}

// Round 12
// 1551.772 us; speedup vs baseline: 1.7529x; 1.3056x over previous
//
#include <hip/hip_runtime.h>

#define BB 8
#define NN 8192
#define RR 2048
#define LL 4
#define TC 61
#define EPSF 1e-6f
#define BN (BB*NN)
#define OUTN (BN*3)
#define CH 32768

typedef unsigned short u16;
typedef unsigned int u32;
typedef _Float16 h2f __attribute__((ext_vector_type(2)));
typedef _Float16 h8 __attribute__((ext_vector_type(8)));
typedef float f4 __attribute__((ext_vector_type(4)));

__device__ __forceinline__ float fd2(u32 a, u32 b, float acc) {
#if __has_builtin(__builtin_amdgcn_fdot2)
  return __builtin_amdgcn_fdot2(__builtin_bit_cast(h2f, a), __builtin_bit_cast(h2f, b), acc, false);
#else
  h2f A = __builtin_bit_cast(h2f, a), B = __builtin_bit_cast(h2f, b);
  return acc + (float)A.x * (float)B.x + (float)A.y * (float)B.y;
#endif
}
__device__ __forceinline__ float dot32(const u32* g, const u32* w) {
  float a0=0.f, a1=0.f, a2=0.f, a3=0.f;
#pragma unroll
  for (int c = 0; c < 32; c += 4) {
    a0 = fd2(g[c+0], w[c+0], a0);
    a1 = fd2(g[c+1], w[c+1], a1);
    a2 = fd2(g[c+2], w[c+2], a2);
    a3 = fd2(g[c+3], w[c+3], a3);
  }
  return (a0+a1)+(a2+a3);
}
__device__ __forceinline__ u32 packf16(float a, float b) {
  h2f h; h.x = (_Float16)a; h.y = (_Float16)b; return __builtin_bit_cast(u32, h);
}
__device__ __forceinline__ u16 f16b(float a) {
  _Float16 h = (_Float16)a; return __builtin_bit_cast(u16, h);
}
__device__ __forceinline__ float f162f(u16 h) { return (float)__builtin_bit_cast(_Float16, h); }
__device__ __forceinline__ float2 unpk(u32 a) {
  h2f h = __builtin_bit_cast(h2f, a); return make_float2((float)h.x, (float)h.y);
}
__device__ __forceinline__ void up8(uint4 A, float* v) {
  float2 t0=unpk(A.x), t1=unpk(A.y), t2=unpk(A.z), t3=unpk(A.w);
  v[0]=t0.x; v[1]=t0.y; v[2]=t1.x; v[3]=t1.y; v[4]=t2.x; v[5]=t2.y; v[6]=t3.x; v[7]=t3.y;
}
__device__ __forceinline__ int kmax_of(int n) {
  int aatom = n & 3, rres = n >> 2;
  return (aatom==0) ? (rres==0 ? 2 : 3)
       : (aatom==1) ? 3
       : (aatom==2) ? (rres==RR-1 ? 3 : 4) : 2;
}

__global__ __launch_bounds__(256) void k_const(float* out, float v) {
  int i = blockIdx.x*256 + threadIdx.x;
  if (i < OUTN) out[i] = v;
}

// ---------- weight pre-pack: old fdot2 layout (139264 u32) + QKV MFMA-frag layout (49152 u32) ----------
struct WSrc { const float* m[11]; };
__global__ __launch_bounds__(256) void k_prep(WSrc s, u32* W16) {
  int i = blockIdx.x*256 + threadIdx.x;   // 188416 items
  if (i < 73728) {                        // 9 [64x64] mats, pairs over dim0
    int m = i >> 13, rr = i & 8191, l = rr >> 11, r2 = rr & 2047;
    int c2 = r2 >> 6, col = r2 & 63;
    const float* src = s.m[m] + l*4096;
    W16[i] = packf16(src[(2*c2)*64 + col], src[(2*c2+1)*64 + col]);
  } else if (i < 106496) {                // ffa [64 x 256]
    int j2 = i - 73728; int l = j2 >> 13, r2 = j2 & 8191;
    int c2 = r2 >> 8, j = r2 & 255;
    const float* src = s.m[9] + l*16384;
    W16[i] = packf16(src[(2*c2)*256 + j], src[(2*c2+1)*256 + j]);
  } else if (i < 139264) {                // ffb [256 x 64]
    int j2 = i - 106496; int l = j2 >> 13, r2 = j2 & 8191;
    int jp = r2 >> 6, e = r2 & 63;
    const float* src = s.m[10] + l*16384;
    W16[i] = packf16(src[(2*jp)*64 + e], src[(2*jp+1)*64 + e]);
  } else {                                // QKV B-fragment order: [l][mat0..5][8 fragblk][256]
    int j2 = i - 139264;
    int l = j2 / 12288, rem = j2 % 12288;
    int m = rem >> 11, r2 = rem & 2047;
    int fb = r2 >> 8, li = r2 & 255;
    int nt = fb >> 1, kc = fb & 1;
    int lane = li >> 2, j = li & 3;
    int c2 = kc*16 + (lane>>4)*4 + j;
    int e  = nt*16 + (lane & 15);
    const float* src = s.m[m] + l*4096;
    W16[i] = packf16(src[(2*c2)*64 + e], src[(2*c2+1)*64 + e]);
  }
}

// ---------- time embedding MLP ----------
__global__ __launch_bounds__(128) void k_te(const float* t, const float* w1, const float* b1,
                                            const float* w2, const float* b2, float* te2) {
  __shared__ float s0[128], s1[128];
  int j = threadIdx.x;
  for (int b = 0; b < BB; ++b) {
    float tv = t[b];
    int i = j & 63;
    float fr = expf(-9.210340371976184f * (float)i * (1.0f/64.0f));
    float em = tv * fr;
    s0[j] = (j < 64) ? sinf(em) : cosf(em);
    __syncthreads();
    float acc = b1[j];
    for (int i2 = 0; i2 < 128; ++i2) acc += s0[i2] * w1[i2*128 + j];
    s1[j] = acc / (1.f + expf(-acc));
    __syncthreads();
    if (j < TC) {
      float a2 = b2[j];
      for (int i2 = 0; i2 < 128; ++i2) a2 += s1[i2] * w2[i2*TC + j];
      te2[b*TC + j] = a2;
    }
    __syncthreads();
  }
}

// ---------- init f0p/f1p + rhat ----------
__global__ __launch_bounds__(256) void k_init(const float* x, const float* win1, const int* nbr,
                                              const float* te2, u32* f0p, u32* f1p, u16* rhat) {
  int tok = blockIdx.x*8 + (threadIdx.x >> 5);
  int c2 = threadIdx.x & 31;
  int b = tok >> 13, n = tok & (NN-1);
  float x0 = x[tok*3+0], x1 = x[tok*3+1], x2 = x[tok*3+2];
  int ca = 2*c2, cb = 2*c2+1;
  float va = (ca < TC) ? te2[b*TC + ca] : (ca == 61 ? x0 : (ca == 62 ? x1 : x2));
  float vb = (cb < TC) ? te2[b*TC + cb] : (cb == 61 ? x0 : (cb == 62 ? x1 : x2));
  f0p[tok*32 + c2] = packf16(va, vb);
  float wa = win1[ca], wb = win1[cb];
  f1p[(tok*3+0)*32 + c2] = packf16(x0*wa, x0*wb);
  f1p[(tok*3+1)*32 + c2] = packf16(x1*wa, x1*wb);
  f1p[(tok*3+2)*32 + c2] = packf16(x2*wa, x2*wb);
  if (c2 < 4) {
    int tj = b*NN + nbr[n*4 + c2];
    float rx = x[tj*3+0] - x0, ry = x[tj*3+1] - x1, rz = x[tj*3+2] - x2;
    float ir = rsqrtf(rx*rx + ry*ry + rz*rz + EPSF);
    rhat[(tok*4+c2)*3 + 0] = f16b(rx * ir);
    rhat[(tok*4+c2)*3 + 1] = f16b(ry * ir);
    rhat[(tok*4+c2)*3 + 2] = f16b(rz * ir);
  }
}

// ---------- kA: LN/vnorm + QKV via MFMA (wave = 16 tokens) ----------
__global__ __launch_bounds__(256) void k_qkv(const u32* W16, int l,
    const u32* f0p, const u32* f1p, int tokb,
    u16* Q0, u16* K0, u16* V0, u16* Q1, u16* K1, u16* V1) {
  __shared__ u32 S[9216];            // 4 waves x (16*36 + 3*16*36)
  int tid = threadIdx.x, wv = tid >> 6, lane = tid & 63;
  u32* sg0 = S + wv*2304;
  u32* sg1 = sg0 + 576;
  int tl16 = (blockIdx.x*4 + wv)*16;
  // ---- norm: 4 lanes per token ----
  {
    int t = lane >> 2, q = lane & 3;
    int gt = tokb + tl16 + t;
    u32 r0[8];
    *(uint4*)(r0)     = *(const uint4*)(f0p + (size_t)gt*32 + q*8);
    *(uint4*)(r0 + 4) = *(const uint4*)(f0p + (size_t)gt*32 + q*8 + 4);
    float s = 0.f, s2 = 0.f;
#pragma unroll
    for (int i = 0; i < 8; ++i) { float2 p = unpk(r0[i]); s += p.x + p.y; s2 += p.x*p.x + p.y*p.y; }
    s  += __shfl_xor(s, 1, 64);  s  += __shfl_xor(s, 2, 64);
    s2 += __shfl_xor(s2, 1, 64); s2 += __shfl_xor(s2, 2, 64);
    float mu = s*(1.f/64.f);
    float ri = rsqrtf(fmaxf(s2*(1.f/64.f)-mu*mu, 0.f) + EPSF);
#pragma unroll
    for (int i = 0; i < 8; ++i) {
      float2 p = unpk(r0[i]);
      sg0[t*36 + q*8 + i] = packf16((p.x-mu)*ri, (p.y-mu)*ri);
    }
    u32 r1[3][8]; float ss = 0.f;
#pragma unroll
    for (int v = 0; v < 3; ++v) {
      *(uint4*)(r1[v])     = *(const uint4*)(f1p + (size_t)(gt*3+v)*32 + q*8);
      *(uint4*)(r1[v] + 4) = *(const uint4*)(f1p + (size_t)(gt*3+v)*32 + q*8 + 4);
#pragma unroll
      for (int i = 0; i < 8; ++i) { float2 p = unpk(r1[v][i]); ss += p.x*p.x + p.y*p.y; }
    }
    ss += __shfl_xor(ss, 1, 64); ss += __shfl_xor(ss, 2, 64);
    float vs = rsqrtf(ss*(1.f/64.f) + EPSF);
#pragma unroll
    for (int v = 0; v < 3; ++v)
#pragma unroll
      for (int i = 0; i < 8; ++i) {
        float2 p = unpk(r1[v][i]);
        sg1[(v*16+t)*36 + q*8 + i] = packf16(p.x*vs, p.y*vs);
      }
  }
  __syncthreads();
  // ---- A-fragments ----
  int arow = lane & 15, aq = lane >> 4;
  h8 ag0[2], ag1[3][2];
#pragma unroll
  for (int kc = 0; kc < 2; ++kc)
    ag0[kc] = __builtin_bit_cast(h8, *(const uint4*)(sg0 + arow*36 + kc*16 + aq*4));
#pragma unroll
  for (int v = 0; v < 3; ++v)
#pragma unroll
    for (int kc = 0; kc < 2; ++kc)
      ag1[v][kc] = __builtin_bit_cast(h8, *(const uint4*)(sg1 + (v*16+arow)*36 + kc*16 + aq*4));
  // ---- MFMA apps ----
  const u32* base = W16 + 139264 + l*12288;
  int mb = (lane>>4)*4, ncol = lane & 15;
  auto proj = [&](const u32* pm, const h8* afr, u16* out, int vstride, int vv) {
#pragma unroll
    for (int nt = 0; nt < 4; ++nt) {
      f4 acc = {0.f, 0.f, 0.f, 0.f};
#pragma unroll
      for (int kc = 0; kc < 2; ++kc) {
        uint4 wb = *(const uint4*)(pm + (nt*2+kc)*256 + lane*4);
        acc = __builtin_amdgcn_mfma_f32_16x16x32_f16(afr[kc], __builtin_bit_cast(h8, wb), acc, 0, 0, 0);
      }
      int e = nt*16 + ncol;
#pragma unroll
      for (int r = 0; r < 4; ++r) {
        int tok = tl16 + mb + r;
        out[((size_t)tok*vstride + vv)*64 + e] = f16b(acc[r]);
      }
    }
  };
  proj(base + 0*2048, ag0, Q0, 1, 0);
  proj(base + 1*2048, ag0, K0, 1, 0);
  proj(base + 2*2048, ag0, V0, 1, 0);
#pragma unroll
  for (int v = 0; v < 3; ++v) proj(base + 3*2048, ag1[v], Q1, 3, v);
#pragma unroll
  for (int v = 0; v < 3; ++v) proj(base + 4*2048, ag1[v], K1, 3, v);
#pragma unroll
  for (int v = 0; v < 3; ++v) proj(base + 5*2048, ag1[v], V1, 3, v);
}

// ---------- kB: gather + attention (wave = 1 token) ----------
__global__ __launch_bounds__(256) void k_attn(const u16* Q0, const u16* K0, const u16* V0,
    const u16* Q1, const u16* K1, const u16* V1, const int* nbr, const u16* rhat,
    int tokb, u16* o0, u16* o1) {
  int tid = threadIdx.x, wv = tid >> 6, e = tid & 63;
  int tl = blockIdx.x*4 + wv;
  int gt = tokb + tl;
  int n = gt & (NN-1);
  int km = kmax_of(n);
  int base = gt - n - tokb;
  int tk[4];
#pragma unroll
  for (int k = 0; k < 4; ++k) tk[k] = nbr[n*4+k] + base;
  float q0 = f162f(Q0[(size_t)tl*64+e]);
  float q1[3];
#pragma unroll
  for (int v = 0; v < 3; ++v) q1[v] = f162f(Q1[(size_t)(tl*3+v)*64+e]);
  float k0r[4], v0r[4], k1r[4][3], v1r[4][3], rh[4][3];
#pragma unroll
  for (int k = 0; k < 4; ++k) {
    k0r[k] = f162f(K0[(size_t)tk[k]*64+e]);
    v0r[k] = f162f(V0[(size_t)tk[k]*64+e]);
#pragma unroll
    for (int v = 0; v < 3; ++v) {
      k1r[k][v] = f162f(K1[(size_t)(tk[k]*3+v)*64+e]);
      v1r[k][v] = f162f(V1[(size_t)(tk[k]*3+v)*64+e]);
      rh[k][v]  = f162f(rhat[(size_t)(gt*4+k)*3+v]);
    }
  }
  float p[4];
#pragma unroll
  for (int k = 0; k < 4; ++k)
    p[k] = q0*k0r[k] + q1[0]*k1r[k][0] + q1[1]*k1r[k][1] + q1[2]*k1r[k][2];
#pragma unroll
  for (int m = 1; m < 16; m <<= 1) {
#pragma unroll
    for (int k = 0; k < 4; ++k) p[k] += __shfl_xor(p[k], m, 64);
  }
  float mx = -1e30f;
#pragma unroll
  for (int k = 0; k < 4; ++k) { p[k] *= 0.25f; if (k < km) mx = fmaxf(mx, p[k]); }
  float aw[4], ssum = 0.f;
#pragma unroll
  for (int k = 0; k < 4; ++k) { aw[k] = (k < km) ? expf(p[k]-mx) : 0.f; ssum += aw[k]; }
  float inv = 1.f / ssum;
  float O0 = 0.f, O1[3] = {0.f,0.f,0.f};
#pragma unroll
  for (int k = 0; k < 4; ++k) {
    float a = aw[k]*inv;
    float vd = v1r[k][0]*rh[k][0] + v1r[k][1]*rh[k][1] + v1r[k][2]*rh[k][2];
    O0 += a*(v0r[k] + vd);
#pragma unroll
    for (int v = 0; v < 3; ++v) O1[v] += a*(v1r[k][v] + v0r[k]*rh[k][v]);
  }
  o0[(size_t)tl*64+e] = f16b(O0);
#pragma unroll
  for (int v = 0; v < 3; ++v) o1[(size_t)(tl*3+v)*64+e] = f16b(O1[v]);
}

// ---------- kCD: out-proj + residual + LN + ffa(silu) ----------
__global__ __launch_bounds__(256) void k_od(const u32* W16, int l,
    const u16* o0, const u16* o1, const u32* f0p, const u32* f1p, int tokb,
    u16* f0mid, u16* f1mid, u16* hbuf) {
  __shared__ u32 S[5120];
  int tid = threadIdx.x, wv = tid >> 6, lane = tid & 63;
  u32* so0 = S + wv*1280; u32* so1 = so0 + 256; u32* sgf = so0 + 1024;
  int tl8 = (blockIdx.x*4 + wv)*8;
  {
    int g8 = lane >> 3, ln = lane & 7;
    int tl = tl8 + g8;
    const u32* o0u = (const u32*)o0;
    *(uint4*)(so0 + g8*32 + ln*4) = *(const uint4*)(o0u + (size_t)tl*32 + ln*4);
    const u32* o1u = (const u32*)o1;
#pragma unroll
    for (int v = 0; v < 3; ++v)
      *(uint4*)(so1 + (v*8+g8)*32 + ln*4) = *(const uint4*)(o1u + (size_t)(tl*3+v)*32 + ln*4);
  }
  __syncthreads();
  int e = lane;
  const u32* po0 = W16 + 6*8192 + l*2048;
  const u32* po1 = W16 + 7*8192 + l*2048;
  const u32* pa  = W16 + 73728 + l*8192;
  u32 w[32];
#pragma unroll 8
  for (int c = 0; c < 32; ++c) w[c] = po0[c*64+e];
  float f0v[8];
#pragma unroll
  for (int t = 0; t < 8; ++t) {
    float2 r = unpk(f0p[(size_t)(tokb+tl8+t)*32 + (e>>1)]);
    f0v[t] = dot32(so0 + t*32, w) + ((e&1) ? r.y : r.x);
    f0mid[(size_t)(tl8+t)*64+e] = f16b(f0v[t]);
  }
  u16* gf16 = (u16*)sgf;
#pragma unroll
  for (int t = 0; t < 8; ++t) {
    float s = f0v[t], s2 = f0v[t]*f0v[t];
#pragma unroll
    for (int m = 1; m < 64; m <<= 1) { s += __shfl_xor(s, m, 64); s2 += __shfl_xor(s2, m, 64); }
    float mu = s*(1.f/64.f);
    float ri = rsqrtf(fmaxf(s2*(1.f/64.f)-mu*mu, 0.f) + EPSF);
    gf16[t*64+e] = f16b((f0v[t]-mu)*ri);
  }
#pragma unroll 8
  for (int c = 0; c < 32; ++c) w[c] = po1[c*64+e];
#pragma unroll
  for (int v = 0; v < 3; ++v)
#pragma unroll
    for (int t = 0; t < 8; ++t) {
      float2 r = unpk(f1p[(size_t)((tokb+tl8+t)*3+v)*32 + (e>>1)]);
      float val = dot32(so1 + (v*8+t)*32, w) + ((e&1) ? r.y : r.x);
      f1mid[(size_t)((tl8+t)*3+v)*64+e] = f16b(val);
    }
  __syncthreads();
#pragma unroll
  for (int s4 = 0; s4 < 4; ++s4) {
    int j = s4*64 + e;
#pragma unroll 8
    for (int c = 0; c < 32; ++c) w[c] = pa[c*256+j];
#pragma unroll
    for (int t = 0; t < 8; ++t) {
      float a = dot32(sgf + t*32, w);
      hbuf[(size_t)(tl8+t)*256 + j] = f16b(a / (1.f + expf(-a)));
    }
  }
}

// ---------- kEF: ffb + residual -> f0p ; vnorm + ff1 + residual -> f1p ----------
__global__ __launch_bounds__(256) void k_fb(const u32* W16, int l, const u16* hbuf,
    const u16* f0mid, const u16* f1mid, int tokb, u32* f0p, u32* f1p) {
  __shared__ u32 S[7168];
  int tid = threadIdx.x, wv = tid >> 6, lane = tid & 63;
  u32* sh = S + wv*1792; u32* sg1 = sh + 1024;
  int tl8 = (blockIdx.x*4 + wv)*8;
  const u32* hu = (const u32*)hbuf;
#pragma unroll
  for (int t = 0; t < 8; ++t) {
    uint2 d = *(const uint2*)(hu + (size_t)(tl8+t)*128 + lane*2);
    sh[t*128 + lane*2] = d.x; sh[t*128 + lane*2 + 1] = d.y;
  }
  {
    int g8 = lane >> 3, ln = lane & 7;
    int tl = tl8 + g8;
    const u32* fmu = (const u32*)f1mid;
    float v1[24]; float ss = 0.f;
#pragma unroll
    for (int v = 0; v < 3; ++v) {
      uint4 A = *(const uint4*)(fmu + (size_t)(tl*3+v)*32 + ln*4);
      up8(A, v1 + v*8);
#pragma unroll
      for (int i = 0; i < 8; ++i) ss += v1[v*8+i]*v1[v*8+i];
    }
#pragma unroll
    for (int m = 1; m < 8; m <<= 1) ss += __shfl_xor(ss, m, 64);
    float vs = rsqrtf(ss*(1.f/64.f) + EPSF);
#pragma unroll
    for (int v = 0; v < 3; ++v)
#pragma unroll
      for (int i = 0; i < 4; ++i)
        sg1[(v*8+g8)*32 + ln*4 + i] = packf16(v1[v*8+2*i]*vs, v1[v*8+2*i+1]*vs);
  }
  __syncthreads();
  int e = lane;
  const u32* pb   = W16 + 106496 + l*8192;
  const u32* pf1w = W16 + 8*8192 + l*2048;
  float acc[8] = {0,0,0,0,0,0,0,0};
  u32 w[32];
  for (int ch = 0; ch < 4; ++ch) {
#pragma unroll 8
    for (int c = 0; c < 32; ++c) w[c] = pb[(ch*32+c)*64+e];
#pragma unroll
    for (int t = 0; t < 8; ++t) acc[t] += dot32(sh + t*128 + ch*32, w);
  }
#pragma unroll
  for (int t = 0; t < 8; ++t) {
    float r = f162f(f0mid[(size_t)(tl8+t)*64+e]) + acc[t];
    float o = __shfl_xor(r, 1, 64);
    if (!(e&1)) f0p[(size_t)(tokb+tl8+t)*32 + (e>>1)] = packf16(r, o);
  }
#pragma unroll 8
  for (int c = 0; c < 32; ++c) w[c] = pf1w[c*64+e];
#pragma unroll
  for (int v = 0; v < 3; ++v)
#pragma unroll
    for (int t = 0; t < 8; ++t) {
      float r = dot32(sg1 + (v*8+t)*32, w) + f162f(f1mid[(size_t)((tl8+t)*3+v)*64+e]);
      float o = __shfl_xor(r, 1, 64);
      if (!(e&1)) f1p[(size_t)((tokb+tl8+t)*3+v)*32 + (e>>1)] = packf16(r, o);
    }
}

// ---------- final score ----------
__global__ __launch_bounds__(256) void k_final(const u32* f1p, const float* wout, const float* bout, float* out) {
  int tok = blockIdx.x*4 + (threadIdx.x >> 6);
  int lane = threadIdx.x & 63;
  float p[3];
#pragma unroll
  for (int v = 0; v < 3; ++v) {
    float2 pr = unpk(f1p[(size_t)(tok*3+v)*32 + (lane>>1)]);
    float x = ((lane & 1) ? pr.y : pr.x) * wout[v*64 + lane];
#pragma unroll
    for (int m = 1; m < 64; m <<= 1) x += __shfl_xor(x, m, 64);
    p[v] = x;
  }
  if (lane < 3) out[tok*3 + lane] = p[lane] + bout[lane];
}

extern "C" void kernel_launch(void* const* d_in, const int* in_sizes, int n_in,
                              void* d_out, int out_size, void* d_ws, size_t ws_size,
                              hipStream_t stream) {
  float* out = (float*)d_out;
  static const int exp23[23] = {196608,196608,8,32768,32768,16384,128,7808,61,64,
                                16384,16384,16384,16384,16384,16384,16384,16384,
                                65536,65536,16384,192,3};
  bool ok23 = (n_in == 23), ok22 = (n_in == 22);
  int bad = -1;
  if (ok23) {
    for (int i = 0; i < 23; ++i) if (in_sizes[i] != exp23[i]) { ok23 = false; bad = i; break; }
  }
  if (!ok23 && ok22) {
    for (int i = 0; i < 22; ++i) {
      int want = (i == 0) ? exp23[0] : exp23[i+1];
      if (in_sizes[i] != want) { ok22 = false; if (bad < 0) bad = i; break; }
    }
  } else ok22 = false;
  if (!ok23 && !ok22) {
    k_const<<<768, 256, 0, stream>>>(out, (float)(3000 + (bad < 0 ? 100 + n_in : bad)));
    return;
  }
  int sh = ok23 ? 0 : -1;
  const int* nbr = (const int*)d_in[3 + sh];
  const float* F[20];
  F[0] = (const float*)d_in[0];
  F[1] = (const float*)d_in[2 + sh];
  for (int j = 0; j < 18; ++j) F[2 + j] = (const float*)d_in[5 + sh + j];

  char* ws = (char*)d_ws;
  u32*   W16  = (u32*)ws;                           // 188416 u32 = 753,664 B
  float* te2  = (float*)(ws + 753664);              // 2,048 B
  u16*   rhat = (u16*)(ws + 755712);                // 1,572,864 B
  u32*   f0p  = (u32*)(ws + 2328576);               // 8,388,608 B
  u32*   f1p  = (u32*)(ws + 10717184);              // 25,165,824 B
  char*  cb   = ws + 35883008;                      // 64 MB chunk area -> end 102,991,872
  u16* Q0 = (u16*)(cb + 0);
  u16* K0 = (u16*)(cb + 4194304);
  u16* V0 = (u16*)(cb + 8388608);
  u16* Q1 = (u16*)(cb + 12582912);
  u16* K1 = (u16*)(cb + 25165824);
  u16* V1 = (u16*)(cb + 37748736);
  u16* o0 = (u16*)(cb + 50331648);
  u16* o1 = (u16*)(cb + 54525952);
  u16* hbuf  = Q1;
  u16* f0mid = V0;
  u16* f1mid = V1;

  WSrc s;
  s.m[0]=F[7]; s.m[1]=F[8]; s.m[2]=F[9]; s.m[3]=F[10]; s.m[4]=F[11]; s.m[5]=F[12];
  s.m[6]=F[13]; s.m[7]=F[14]; s.m[8]=F[17]; s.m[9]=F[15]; s.m[10]=F[16];

  k_prep<<<736, 256, 0, stream>>>(s, W16);
  k_te<<<1, 128, 0, stream>>>(F[1], F[2], F[3], F[4], F[5], te2);
  k_init<<<BN/8, 256, 0, stream>>>(F[0], F[6], nbr, te2, f0p, f1p, rhat);
  for (int c = 0; c < 2; ++c) {
    int tokb = c * CH;
    for (int l = 0; l < LL; ++l) {
      k_qkv<<<CH/64, 256, 0, stream>>>(W16, l, f0p, f1p, tokb, Q0, K0, V0, Q1, K1, V1);
      k_attn<<<CH/4, 256, 0, stream>>>(Q0, K0, V0, Q1, K1, V1, nbr, rhat, tokb, o0, o1);
      k_od<<<CH/32, 256, 0, stream>>>(W16, l, o0, o1, f0p, f1p, tokb, f0mid, f1mid, hbuf);
      k_fb<<<CH/32, 256, 0, stream>>>(W16, l, hbuf, f0mid, f1mid, tokb, f0p, f1p);
    }
  }
  k_final<<<BN/4, 256, 0, stream>>>(f1p, F[18], F[19], out);
}

// Round 13
// 655.777 us; speedup vs baseline: 4.1479x; 2.3663x over previous
//
#include <hip/hip_runtime.h>

#define BB 8
#define NN 8192
#define RR 2048
#define LL 4
#define TC 61
#define EPSF 1e-6f
#define BN (BB*NN)
#define OUTN (BN*3)
#define CH 32768

typedef unsigned short u16;
typedef unsigned int u32;
typedef _Float16 h2f __attribute__((ext_vector_type(2)));
typedef _Float16 h8 __attribute__((ext_vector_type(8)));
typedef float f4 __attribute__((ext_vector_type(4)));

__device__ __forceinline__ u32 packf16(float a, float b) {
  h2f h; h.x = (_Float16)a; h.y = (_Float16)b; return __builtin_bit_cast(u32, h);
}
__device__ __forceinline__ u16 f16b(float a) {
  _Float16 h = (_Float16)a; return __builtin_bit_cast(u16, h);
}
__device__ __forceinline__ float f162f(u16 h) { return (float)__builtin_bit_cast(_Float16, h); }
__device__ __forceinline__ float2 unpk(u32 a) {
  h2f h = __builtin_bit_cast(h2f, a); return make_float2((float)h.x, (float)h.y);
}
__device__ __forceinline__ int kmax_of(int n) {
  int aatom = n & 3, rres = n >> 2;
  return (aatom==0) ? (rres==0 ? 2 : 3)
       : (aatom==1) ? 3
       : (aatom==2) ? (rres==RR-1 ? 3 : 4) : 2;
}

__global__ __launch_bounds__(256) void k_const(float* out, float v) {
  int i = blockIdx.x*256 + threadIdx.x;
  if (i < OUTN) out[i] = v;
}

// ---------- weight pre-pack ----------
// [0..139264): legacy pair-packed (unused paths kept for k_te-free mats? only 0..73728 9-mat region unused now except none; harmless)
// [139264..188416): QKV B-frags   [l][mat0..5][8 fb][256]
// [188416..278528): odfb B-frags  [l][Wo0 8fb][Wo1 8fb][Wff1 8fb][ffa 32fb][ffb 32fb] x 256
struct WSrc { const float* m[11]; };
__global__ __launch_bounds__(256) void k_prep(WSrc s, u32* W16) {
  int i = blockIdx.x*256 + threadIdx.x;   // 278528 items
  if (i >= 278528) return;
  if (i < 73728) {
    int m = i >> 13, rr = i & 8191, l = rr >> 11, r2 = rr & 2047;
    int c2 = r2 >> 6, col = r2 & 63;
    const float* src = s.m[m] + l*4096;
    W16[i] = packf16(src[(2*c2)*64 + col], src[(2*c2+1)*64 + col]);
  } else if (i < 106496) {
    int j2 = i - 73728; int l = j2 >> 13, r2 = j2 & 8191;
    int c2 = r2 >> 8, j = r2 & 255;
    const float* src = s.m[9] + l*16384;
    W16[i] = packf16(src[(2*c2)*256 + j], src[(2*c2+1)*256 + j]);
  } else if (i < 139264) {
    int j2 = i - 106496; int l = j2 >> 13, r2 = j2 & 8191;
    int jp = r2 >> 6, e = r2 & 63;
    const float* src = s.m[10] + l*16384;
    W16[i] = packf16(src[(2*jp)*64 + e], src[(2*jp+1)*64 + e]);
  } else if (i < 188416) {                // QKV B-frags
    int j2 = i - 139264;
    int l = j2 / 12288, rem = j2 % 12288;
    int m = rem >> 11, r2 = rem & 2047;
    int fb = r2 >> 8, li = r2 & 255;
    int nt = fb >> 1, kc = fb & 1;
    int lane = li >> 2, j = li & 3;
    int c2 = kc*16 + (lane>>4)*4 + j;
    int e  = nt*16 + (lane & 15);
    const float* src = s.m[m] + l*4096;
    W16[i] = packf16(src[(2*c2)*64 + e], src[(2*c2+1)*64 + e]);
  } else {                                // odfb B-frags
    int j2 = i - 188416;
    int l = j2 / 22528, rem = j2 % 22528;
    int li, fb, msel, N;
    const float* srcb;
    if (rem < 6144) {                     // Wo0 / Wo1 / Wff1 (64x64)
      msel = 6 + (rem >> 11);             // 6,7,8
      int r2 = rem & 2047;
      fb = r2 >> 8; li = r2 & 255;
      srcb = s.m[msel] + l*4096; N = 64;
      int nt = fb >> 1, kc = fb & 1;
      int lane = li >> 2, j = li & 3;
      int c2 = kc*16 + (lane>>4)*4 + j;
      int e  = nt*16 + (lane & 15);
      W16[i] = packf16(srcb[(2*c2)*N + e], srcb[(2*c2+1)*N + e]);
    } else if (rem < 14336) {             // ffa (64x256)
      int r2 = rem - 6144;
      fb = r2 >> 8; li = r2 & 255;
      srcb = s.m[9] + l*16384; N = 256;
      int nt = fb >> 1, kc = fb & 1;
      int lane = li >> 2, j = li & 3;
      int c2 = kc*16 + (lane>>4)*4 + j;
      int e  = nt*16 + (lane & 15);
      W16[i] = packf16(srcb[(2*c2)*N + e], srcb[(2*c2+1)*N + e]);
    } else {                              // ffb (256x64), fb = nt*8+kc
      int r2 = rem - 14336;
      fb = r2 >> 8; li = r2 & 255;
      srcb = s.m[10] + l*16384; N = 64;
      int nt = fb >> 3, kc = fb & 7;
      int lane = li >> 2, j = li & 3;
      int c2 = kc*16 + (lane>>4)*4 + j;
      int e  = nt*16 + (lane & 15);
      W16[i] = packf16(srcb[(2*c2)*N + e], srcb[(2*c2+1)*N + e]);
    }
  }
}

// ---------- time embedding MLP ----------
__global__ __launch_bounds__(128) void k_te(const float* t, const float* w1, const float* b1,
                                            const float* w2, const float* b2, float* te2) {
  __shared__ float s0[128], s1[128];
  int j = threadIdx.x;
  for (int b = 0; b < BB; ++b) {
    float tv = t[b];
    int i = j & 63;
    float fr = expf(-9.210340371976184f * (float)i * (1.0f/64.0f));
    float em = tv * fr;
    s0[j] = (j < 64) ? sinf(em) : cosf(em);
    __syncthreads();
    float acc = b1[j];
    for (int i2 = 0; i2 < 128; ++i2) acc += s0[i2] * w1[i2*128 + j];
    s1[j] = acc / (1.f + expf(-acc));
    __syncthreads();
    if (j < TC) {
      float a2 = b2[j];
      for (int i2 = 0; i2 < 128; ++i2) a2 += s1[i2] * w2[i2*TC + j];
      te2[b*TC + j] = a2;
    }
    __syncthreads();
  }
}

// ---------- init f0p/f1p + rhat ----------
__global__ __launch_bounds__(256) void k_init(const float* x, const float* win1, const int* nbr,
                                              const float* te2, u32* f0p, u32* f1p, u16* rhat) {
  int tok = blockIdx.x*8 + (threadIdx.x >> 5);
  int c2 = threadIdx.x & 31;
  int b = tok >> 13, n = tok & (NN-1);
  float x0 = x[tok*3+0], x1 = x[tok*3+1], x2 = x[tok*3+2];
  int ca = 2*c2, cb = 2*c2+1;
  float va = (ca < TC) ? te2[b*TC + ca] : (ca == 61 ? x0 : (ca == 62 ? x1 : x2));
  float vb = (cb < TC) ? te2[b*TC + cb] : (cb == 61 ? x0 : (cb == 62 ? x1 : x2));
  f0p[tok*32 + c2] = packf16(va, vb);
  float wa = win1[ca], wb = win1[cb];
  f1p[(tok*3+0)*32 + c2] = packf16(x0*wa, x0*wb);
  f1p[(tok*3+1)*32 + c2] = packf16(x1*wa, x1*wb);
  f1p[(tok*3+2)*32 + c2] = packf16(x2*wa, x2*wb);
  if (c2 < 4) {
    int tj = b*NN + nbr[n*4 + c2];
    float rx = x[tj*3+0] - x0, ry = x[tj*3+1] - x1, rz = x[tj*3+2] - x2;
    float ir = rsqrtf(rx*rx + ry*ry + rz*rz + EPSF);
    rhat[(tok*4+c2)*3 + 0] = f16b(rx * ir);
    rhat[(tok*4+c2)*3 + 1] = f16b(ry * ir);
    rhat[(tok*4+c2)*3 + 2] = f16b(rz * ir);
  }
}

// ---------- kA: LN/vnorm + QKV via MFMA (wave = 16 tokens) ----------
__global__ __launch_bounds__(256) void k_qkv(const u32* W16, int l,
    const u32* f0p, const u32* f1p, int tokb,
    u16* Q0, u16* K0, u16* V0, u16* Q1, u16* K1, u16* V1) {
  __shared__ u32 S[9216];
  int tid = threadIdx.x, wv = tid >> 6, lane = tid & 63;
  u32* sg0 = S + wv*2304;
  u32* sg1 = sg0 + 576;
  int tl16 = (blockIdx.x*4 + wv)*16;
  {
    int t = lane >> 2, q = lane & 3;
    int gt = tokb + tl16 + t;
    u32 r0[8];
    *(uint4*)(r0)     = *(const uint4*)(f0p + (size_t)gt*32 + q*8);
    *(uint4*)(r0 + 4) = *(const uint4*)(f0p + (size_t)gt*32 + q*8 + 4);
    float s = 0.f, s2 = 0.f;
#pragma unroll
    for (int i = 0; i < 8; ++i) { float2 p = unpk(r0[i]); s += p.x + p.y; s2 += p.x*p.x + p.y*p.y; }
    s  += __shfl_xor(s, 1, 64);  s  += __shfl_xor(s, 2, 64);
    s2 += __shfl_xor(s2, 1, 64); s2 += __shfl_xor(s2, 2, 64);
    float mu = s*(1.f/64.f);
    float ri = rsqrtf(fmaxf(s2*(1.f/64.f)-mu*mu, 0.f) + EPSF);
#pragma unroll
    for (int i = 0; i < 8; ++i) {
      float2 p = unpk(r0[i]);
      sg0[t*36 + q*8 + i] = packf16((p.x-mu)*ri, (p.y-mu)*ri);
    }
    u32 r1[3][8]; float ss = 0.f;
#pragma unroll
    for (int v = 0; v < 3; ++v) {
      *(uint4*)(r1[v])     = *(const uint4*)(f1p + (size_t)(gt*3+v)*32 + q*8);
      *(uint4*)(r1[v] + 4) = *(const uint4*)(f1p + (size_t)(gt*3+v)*32 + q*8 + 4);
#pragma unroll
      for (int i = 0; i < 8; ++i) { float2 p = unpk(r1[v][i]); ss += p.x*p.x + p.y*p.y; }
    }
    ss += __shfl_xor(ss, 1, 64); ss += __shfl_xor(ss, 2, 64);
    float vs = rsqrtf(ss*(1.f/64.f) + EPSF);
#pragma unroll
    for (int v = 0; v < 3; ++v)
#pragma unroll
      for (int i = 0; i < 8; ++i) {
        float2 p = unpk(r1[v][i]);
        sg1[(v*16+t)*36 + q*8 + i] = packf16(p.x*vs, p.y*vs);
      }
  }
  __syncthreads();
  int arow = lane & 15, aq = lane >> 4;
  h8 ag0[2], ag1[3][2];
#pragma unroll
  for (int kc = 0; kc < 2; ++kc)
    ag0[kc] = __builtin_bit_cast(h8, *(const uint4*)(sg0 + arow*36 + kc*16 + aq*4));
#pragma unroll
  for (int v = 0; v < 3; ++v)
#pragma unroll
    for (int kc = 0; kc < 2; ++kc)
      ag1[v][kc] = __builtin_bit_cast(h8, *(const uint4*)(sg1 + (v*16+arow)*36 + kc*16 + aq*4));
  const u32* base = W16 + 139264 + l*12288;
  int mb = (lane>>4)*4, ncol = lane & 15;
  auto proj = [&](const u32* pm, const h8* afr, u16* out, int vstride, int vv) {
#pragma unroll
    for (int nt = 0; nt < 4; ++nt) {
      f4 acc = {0.f, 0.f, 0.f, 0.f};
#pragma unroll
      for (int kc = 0; kc < 2; ++kc) {
        uint4 wb = *(const uint4*)(pm + (nt*2+kc)*256 + lane*4);
        acc = __builtin_amdgcn_mfma_f32_16x16x32_f16(afr[kc], __builtin_bit_cast(h8, wb), acc, 0, 0, 0);
      }
      int e = nt*16 + ncol;
#pragma unroll
      for (int r = 0; r < 4; ++r) {
        int tok = tl16 + mb + r;
        out[((size_t)tok*vstride + vv)*64 + e] = f16b(acc[r]);
      }
    }
  };
  proj(base + 0*2048, ag0, Q0, 1, 0);
  proj(base + 1*2048, ag0, K0, 1, 0);
  proj(base + 2*2048, ag0, V0, 1, 0);
#pragma unroll
  for (int v = 0; v < 3; ++v) proj(base + 3*2048, ag1[v], Q1, 3, v);
#pragma unroll
  for (int v = 0; v < 3; ++v) proj(base + 4*2048, ag1[v], K1, 3, v);
#pragma unroll
  for (int v = 0; v < 3; ++v) proj(base + 5*2048, ag1[v], V1, 3, v);
}

// ---------- kB: gather + attention (wave = 1 token) ----------
__global__ __launch_bounds__(256) void k_attn(const u16* Q0, const u16* K0, const u16* V0,
    const u16* Q1, const u16* K1, const u16* V1, const int* nbr, const u16* rhat,
    int tokb, u16* o0, u16* o1) {
  int tid = threadIdx.x, wv = tid >> 6, e = tid & 63;
  int tl = blockIdx.x*4 + wv;
  int gt = tokb + tl;
  int n = gt & (NN-1);
  int km = kmax_of(n);
  int base = gt - n - tokb;
  int tk[4];
#pragma unroll
  for (int k = 0; k < 4; ++k) tk[k] = nbr[n*4+k] + base;
  float q0 = f162f(Q0[(size_t)tl*64+e]);
  float q1[3];
#pragma unroll
  for (int v = 0; v < 3; ++v) q1[v] = f162f(Q1[(size_t)(tl*3+v)*64+e]);
  float k0r[4], v0r[4], k1r[4][3], v1r[4][3], rh[4][3];
#pragma unroll
  for (int k = 0; k < 4; ++k) {
    k0r[k] = f162f(K0[(size_t)tk[k]*64+e]);
    v0r[k] = f162f(V0[(size_t)tk[k]*64+e]);
#pragma unroll
    for (int v = 0; v < 3; ++v) {
      k1r[k][v] = f162f(K1[(size_t)(tk[k]*3+v)*64+e]);
      v1r[k][v] = f162f(V1[(size_t)(tk[k]*3+v)*64+e]);
      rh[k][v]  = f162f(rhat[(size_t)(gt*4+k)*3+v]);
    }
  }
  float p[4];
#pragma unroll
  for (int k = 0; k < 4; ++k)
    p[k] = q0*k0r[k] + q1[0]*k1r[k][0] + q1[1]*k1r[k][1] + q1[2]*k1r[k][2];
#pragma unroll
  for (int m = 1; m < 16; m <<= 1) {
#pragma unroll
    for (int k = 0; k < 4; ++k) p[k] += __shfl_xor(p[k], m, 64);
  }
  float mx = -1e30f;
#pragma unroll
  for (int k = 0; k < 4; ++k) { p[k] *= 0.25f; if (k < km) mx = fmaxf(mx, p[k]); }
  float aw[4], ssum = 0.f;
#pragma unroll
  for (int k = 0; k < 4; ++k) { aw[k] = (k < km) ? expf(p[k]-mx) : 0.f; ssum += aw[k]; }
  float inv = 1.f / ssum;
  float O0 = 0.f, O1[3] = {0.f,0.f,0.f};
#pragma unroll
  for (int k = 0; k < 4; ++k) {
    float a = aw[k]*inv;
    float vd = v1r[k][0]*rh[k][0] + v1r[k][1]*rh[k][1] + v1r[k][2]*rh[k][2];
    O0 += a*(v0r[k] + vd);
#pragma unroll
    for (int v = 0; v < 3; ++v) O1[v] += a*(v1r[k][v] + v0r[k]*rh[k][v]);
  }
  o0[(size_t)tl*64+e] = f16b(O0);
#pragma unroll
  for (int v = 0; v < 3; ++v) o1[(size_t)(tl*3+v)*64+e] = f16b(O1[v]);
}

// ---------- kC: fused out-proj + FF via MFMA (wave = 16 tokens) ----------
__global__ __launch_bounds__(256) void k_odfb(const u32* W16, int l,
    const u16* o0, const u16* o1, int tokb, u32* f0p, u32* f1p) {
  __shared__ u32 S[11008];          // 4 waves x 2752
  int tid = threadIdx.x, wv = tid >> 6, lane = tid & 63;
  u32* sw  = S + wv*2752;
  u32* sg1 = sw;                    // 1728 u32 (f1 phase)
  u32* gg  = sw;                    // 576 u32 (f0 phase, aliases sg1)
  u32* hh  = sw + 576;              // 2176 u32 (16 x 136)
  int tl16 = (blockIdx.x*4 + wv)*16;
  int arow = lane & 15, aq = lane >> 4;
  int quad = lane >> 4, ncol = lane & 15, mb = quad*4;
  const u32* Wf  = W16 + 188416 + l*22528;
  const u32* po0f = Wf, *po1f = Wf + 2048, *pf1f = Wf + 4096, *paf = Wf + 6144, *pbf = Wf + 14336;
  const u32* o0u = (const u32*)o0;
  const u32* o1u = (const u32*)o1;

  // ---- f1 path: Wo1 + residual ----
  h8 a1[3][2];
#pragma unroll
  for (int v = 0; v < 3; ++v)
#pragma unroll
    for (int kc = 0; kc < 2; ++kc)
      a1[v][kc] = __builtin_bit_cast(h8, *(const uint4*)(o1u + ((size_t)(tl16+arow)*3+v)*32 + kc*16 + aq*4));
  float f1m[3][4][4];
#pragma unroll
  for (int v = 0; v < 3; ++v)
#pragma unroll
    for (int nt = 0; nt < 4; ++nt) {
      f4 acc = {0.f,0.f,0.f,0.f};
#pragma unroll
      for (int kc = 0; kc < 2; ++kc) {
        uint4 wb = *(const uint4*)(po1f + (nt*2+kc)*256 + lane*4);
        acc = __builtin_amdgcn_mfma_f32_16x16x32_f16(a1[v][kc], __builtin_bit_cast(h8, wb), acc, 0, 0, 0);
      }
#pragma unroll
      for (int r = 0; r < 4; ++r) {
        int gt = tokb + tl16 + mb + r;
        float2 p = unpk(f1p[((size_t)gt*3+v)*32 + nt*8 + (ncol>>1)]);
        f1m[v][nt][r] = acc[r] + ((ncol&1) ? p.y : p.x);
      }
    }
  // vnorm per row
  float vs[4];
#pragma unroll
  for (int r = 0; r < 4; ++r) {
    float ss = 0.f;
#pragma unroll
    for (int v = 0; v < 3; ++v)
#pragma unroll
      for (int nt = 0; nt < 4; ++nt) ss += f1m[v][nt][r]*f1m[v][nt][r];
    ss += __shfl_xor(ss, 1, 64); ss += __shfl_xor(ss, 2, 64);
    ss += __shfl_xor(ss, 4, 64); ss += __shfl_xor(ss, 8, 64);
    vs[r] = rsqrtf(ss*(1.f/64.f) + EPSF);
  }
  {
    u16* sg1h = (u16*)sg1;
#pragma unroll
    for (int v = 0; v < 3; ++v)
#pragma unroll
      for (int nt = 0; nt < 4; ++nt)
#pragma unroll
        for (int r = 0; r < 4; ++r)
          sg1h[v*1152 + (mb+r)*72 + nt*16 + ncol] = f16b(f1m[v][nt][r]*vs[r]);
  }
  __syncthreads();
  // ff1 + residual -> f1p
#pragma unroll
  for (int v = 0; v < 3; ++v)
#pragma unroll
    for (int nt = 0; nt < 4; ++nt) {
      f4 acc = {0.f,0.f,0.f,0.f};
#pragma unroll
      for (int kc = 0; kc < 2; ++kc) {
        h8 af = __builtin_bit_cast(h8, *(const uint4*)(sg1 + v*576 + arow*36 + kc*16 + aq*4));
        uint4 wb = *(const uint4*)(pf1f + (nt*2+kc)*256 + lane*4);
        acc = __builtin_amdgcn_mfma_f32_16x16x32_f16(af, __builtin_bit_cast(h8, wb), acc, 0, 0, 0);
      }
#pragma unroll
      for (int r = 0; r < 4; ++r) {
        int gt = tokb + tl16 + mb + r;
        float val = acc[r] + f1m[v][nt][r];
        float par = __shfl_xor(val, 1, 64);
        if (!(ncol & 1))
          f1p[((size_t)gt*3+v)*32 + nt*8 + (ncol>>1)] = packf16(val, par);
      }
    }
  __syncthreads();   // all waves done reading sg1 (gg aliases it)

  // ---- f0 path: Wo0 + residual ----
  h8 a0[2];
#pragma unroll
  for (int kc = 0; kc < 2; ++kc)
    a0[kc] = __builtin_bit_cast(h8, *(const uint4*)(o0u + (size_t)(tl16+arow)*32 + kc*16 + aq*4));
  float f0m[4][4];
#pragma unroll
  for (int nt = 0; nt < 4; ++nt) {
    f4 acc = {0.f,0.f,0.f,0.f};
#pragma unroll
    for (int kc = 0; kc < 2; ++kc) {
      uint4 wb = *(const uint4*)(po0f + (nt*2+kc)*256 + lane*4);
      acc = __builtin_amdgcn_mfma_f32_16x16x32_f16(a0[kc], __builtin_bit_cast(h8, wb), acc, 0, 0, 0);
    }
#pragma unroll
    for (int r = 0; r < 4; ++r) {
      int gt = tokb + tl16 + mb + r;
      float2 p = unpk(f0p[(size_t)gt*32 + nt*8 + (ncol>>1)]);
      f0m[nt][r] = acc[r] + ((ncol&1) ? p.y : p.x);
    }
  }
  // LN per row
  float mu[4], ri[4];
#pragma unroll
  for (int r = 0; r < 4; ++r) {
    float s = 0.f, s2 = 0.f;
#pragma unroll
    for (int nt = 0; nt < 4; ++nt) { s += f0m[nt][r]; s2 += f0m[nt][r]*f0m[nt][r]; }
    s  += __shfl_xor(s, 1, 64);  s  += __shfl_xor(s, 2, 64);
    s  += __shfl_xor(s, 4, 64);  s  += __shfl_xor(s, 8, 64);
    s2 += __shfl_xor(s2, 1, 64); s2 += __shfl_xor(s2, 2, 64);
    s2 += __shfl_xor(s2, 4, 64); s2 += __shfl_xor(s2, 8, 64);
    mu[r] = s*(1.f/64.f);
    ri[r] = rsqrtf(fmaxf(s2*(1.f/64.f)-mu[r]*mu[r], 0.f) + EPSF);
  }
  {
    u16* gh = (u16*)gg;
#pragma unroll
    for (int nt = 0; nt < 4; ++nt)
#pragma unroll
      for (int r = 0; r < 4; ++r)
        gh[(mb+r)*72 + nt*16 + ncol] = f16b((f0m[nt][r]-mu[r])*ri[r]);
  }
  __syncthreads();
  // ffa + silu -> h
  {
    h8 ga[2];
#pragma unroll
    for (int kc = 0; kc < 2; ++kc)
      ga[kc] = __builtin_bit_cast(h8, *(const uint4*)(gg + arow*36 + kc*16 + aq*4));
    u16* hhh = (u16*)hh;
#pragma unroll
    for (int nt16 = 0; nt16 < 16; ++nt16) {
      f4 acc = {0.f,0.f,0.f,0.f};
#pragma unroll
      for (int kc = 0; kc < 2; ++kc) {
        uint4 wb = *(const uint4*)(paf + (nt16*2+kc)*256 + lane*4);
        acc = __builtin_amdgcn_mfma_f32_16x16x32_f16(ga[kc], __builtin_bit_cast(h8, wb), acc, 0, 0, 0);
      }
#pragma unroll
      for (int r = 0; r < 4; ++r) {
        float a = acc[r];
        hhh[(mb+r)*272 + nt16*16 + ncol] = f16b(a / (1.f + expf(-a)));
      }
    }
  }
  __syncthreads();
  // ffb + residual -> f0p
#pragma unroll
  for (int nt = 0; nt < 4; ++nt) {
    f4 acc = {0.f,0.f,0.f,0.f};
#pragma unroll
    for (int kc = 0; kc < 8; ++kc) {
      h8 af = __builtin_bit_cast(h8, *(const uint4*)(hh + arow*136 + kc*16 + aq*4));
      uint4 wb = *(const uint4*)(pbf + (nt*8+kc)*256 + lane*4);
      acc = __builtin_amdgcn_mfma_f32_16x16x32_f16(af, __builtin_bit_cast(h8, wb), acc, 0, 0, 0);
    }
#pragma unroll
    for (int r = 0; r < 4; ++r) {
      int gt = tokb + tl16 + mb + r;
      float val = acc[r] + f0m[nt][r];
      float par = __shfl_xor(val, 1, 64);
      if (!(ncol & 1))
        f0p[(size_t)gt*32 + nt*8 + (ncol>>1)] = packf16(val, par);
    }
  }
}

// ---------- final score ----------
__global__ __launch_bounds__(256) void k_final(const u32* f1p, const float* wout, const float* bout, float* out) {
  int tok = blockIdx.x*4 + (threadIdx.x >> 6);
  int lane = threadIdx.x & 63;
  float p[3];
#pragma unroll
  for (int v = 0; v < 3; ++v) {
    float2 pr = unpk(f1p[(size_t)(tok*3+v)*32 + (lane>>1)]);
    float x = ((lane & 1) ? pr.y : pr.x) * wout[v*64 + lane];
#pragma unroll
    for (int m = 1; m < 64; m <<= 1) x += __shfl_xor(x, m, 64);
    p[v] = x;
  }
  if (lane < 3) out[tok*3 + lane] = p[lane] + bout[lane];
}

extern "C" void kernel_launch(void* const* d_in, const int* in_sizes, int n_in,
                              void* d_out, int out_size, void* d_ws, size_t ws_size,
                              hipStream_t stream) {
  float* out = (float*)d_out;
  static const int exp23[23] = {196608,196608,8,32768,32768,16384,128,7808,61,64,
                                16384,16384,16384,16384,16384,16384,16384,16384,
                                65536,65536,16384,192,3};
  bool ok23 = (n_in == 23), ok22 = (n_in == 22);
  int bad = -1;
  if (ok23) {
    for (int i = 0; i < 23; ++i) if (in_sizes[i] != exp23[i]) { ok23 = false; bad = i; break; }
  }
  if (!ok23 && ok22) {
    for (int i = 0; i < 22; ++i) {
      int want = (i == 0) ? exp23[0] : exp23[i+1];
      if (in_sizes[i] != want) { ok22 = false; if (bad < 0) bad = i; break; }
    }
  } else ok22 = false;
  if (!ok23 && !ok22) {
    k_const<<<768, 256, 0, stream>>>(out, (float)(3000 + (bad < 0 ? 100 + n_in : bad)));
    return;
  }
  int sh = ok23 ? 0 : -1;
  const int* nbr = (const int*)d_in[3 + sh];
  const float* F[20];
  F[0] = (const float*)d_in[0];
  F[1] = (const float*)d_in[2 + sh];
  for (int j = 0; j < 18; ++j) F[2 + j] = (const float*)d_in[5 + sh + j];

  char* ws = (char*)d_ws;
  u32*   W16  = (u32*)ws;                           // 278528 u32 = 1,114,112 B
  float* te2  = (float*)(ws + 1114112);             // 2,048 B
  u16*   rhat = (u16*)(ws + 1116160);               // 1,572,864 B
  u32*   f0p  = (u32*)(ws + 2689024);               // 8,388,608 B
  u32*   f1p  = (u32*)(ws + 11077632);              // 25,165,824 B
  char*  cb   = ws + 36243456;                      // chunk area -> end 103,352,320
  u16* Q0 = (u16*)(cb + 0);
  u16* K0 = (u16*)(cb + 4194304);
  u16* V0 = (u16*)(cb + 8388608);
  u16* Q1 = (u16*)(cb + 12582912);
  u16* K1 = (u16*)(cb + 25165824);
  u16* V1 = (u16*)(cb + 37748736);
  u16* o0 = (u16*)(cb + 50331648);
  u16* o1 = (u16*)(cb + 54525952);

  WSrc s;
  s.m[0]=F[7]; s.m[1]=F[8]; s.m[2]=F[9]; s.m[3]=F[10]; s.m[4]=F[11]; s.m[5]=F[12];
  s.m[6]=F[13]; s.m[7]=F[14]; s.m[8]=F[17]; s.m[9]=F[15]; s.m[10]=F[16];

  k_prep<<<1088, 256, 0, stream>>>(s, W16);
  k_te<<<1, 128, 0, stream>>>(F[1], F[2], F[3], F[4], F[5], te2);
  k_init<<<BN/8, 256, 0, stream>>>(F[0], F[6], nbr, te2, f0p, f1p, rhat);
  for (int c = 0; c < 2; ++c) {
    int tokb = c * CH;
    for (int l = 0; l < LL; ++l) {
      k_qkv<<<CH/64, 256, 0, stream>>>(W16, l, f0p, f1p, tokb, Q0, K0, V0, Q1, K1, V1);
      k_attn<<<CH/4, 256, 0, stream>>>(Q0, K0, V0, Q1, K1, V1, nbr, rhat, tokb, o0, o1);
      k_odfb<<<CH/64, 256, 0, stream>>>(W16, l, o0, o1, tokb, f0p, f1p);
    }
  }
  k_final<<<BN/4, 256, 0, stream>>>(f1p, F[18], F[19], out);
}